// Round 3
// baseline (234.564 us; speedup 1.0000x reference)
//
#include <hip/hip_runtime.h>
#include <cstddef>
#include <cstdint>

#define B_ 2
#define T_ 4
#define N_ 1024
#define FIN_ 256
#define H_ 8
#define D_ 128
#define SLOPE_ 0.2f

typedef __attribute__((ext_vector_type(8))) short short8;
typedef __attribute__((ext_vector_type(4))) float f32x4;

__device__ inline unsigned short f2bf(float f) {
    uint32_t u = __float_as_uint(f);
    uint32_t r = (u + 0x7fffu + ((u >> 16) & 1u)) >> 16;   // RNE
    return (unsigned short)r;
}

// ---------------------------------------------------------------------------
// Kernel 0 (prep, region-dispatched by blockIdx.x):
//   [0,128)      : pack adj -> adjbits (bit j of word [i][j/32])
//   [128,1152)   : h fp32 -> h_bf bf16 (same [bt][n][s] layout)
//   [1152,1216)  : W [s][hk] -> Wt_bf [hk][s] bf16 (LDS 64x64 tile transpose)
//   [1216,1232)  : wa[s][head*2+st] = sum_d W[s][head*128+d]*a[head*256+st*128+d]
// ---------------------------------------------------------------------------
__global__ __launch_bounds__(256) void k_prep(const float* __restrict__ h,
                                              const int* __restrict__ adj,
                                              const float* __restrict__ W,
                                              const float* __restrict__ a,
                                              unsigned short* __restrict__ h_bf,
                                              unsigned short* __restrict__ Wt_bf,
                                              uint32_t* __restrict__ adjbits,
                                              float* __restrict__ wa) {
    __shared__ float wl[64][68];
    const int bid = blockIdx.x, tid = threadIdx.x;
    if (bid < 128) {                      // ---- adj pack
        const int w = bid * 256 + tid;    // 0..32767
        const int i = w >> 5, jw = w & 31;
        const int4* p = (const int4*)(adj + (size_t)i * N_ + jw * 32);
        uint32_t bits = 0;
        #pragma unroll
        for (int q = 0; q < 8; ++q) {
            const int4 v = p[q];
            bits |= (uint32_t)(v.x > 0) << (q * 4 + 0);
            bits |= (uint32_t)(v.y > 0) << (q * 4 + 1);
            bits |= (uint32_t)(v.z > 0) << (q * 4 + 2);
            bits |= (uint32_t)(v.w > 0) << (q * 4 + 3);
        }
        adjbits[w] = bits;
    } else if (bid < 1152) {              // ---- h -> bf16, 8 elems/thread
        const size_t base = ((size_t)(bid - 128) * 256 + tid) * 8;
        const float4 v0 = *(const float4*)(h + base);
        const float4 v1 = *(const float4*)(h + base + 4);
        unsigned short ob[8];
        ob[0] = f2bf(v0.x); ob[1] = f2bf(v0.y); ob[2] = f2bf(v0.z); ob[3] = f2bf(v0.w);
        ob[4] = f2bf(v1.x); ob[5] = f2bf(v1.y); ob[6] = f2bf(v1.z); ob[7] = f2bf(v1.w);
        *(uint4*)(h_bf + base) = *(uint4*)&ob[0];
    } else if (bid < 1216) {              // ---- W transpose -> bf16
        const int tb  = bid - 1152;
        const int hk0 = (tb >> 2) * 64;
        const int s0  = (tb & 3) * 64;
        {
            const int r  = tid >> 2;          // s_local
            const int c0 = (tid & 3) * 16;    // hk_local chunk
            #pragma unroll
            for (int k = 0; k < 4; ++k)
                *(float4*)&wl[r][c0 + k * 4] =
                    *(const float4*)(W + (size_t)(s0 + r) * (H_ * D_) + hk0 + c0 + k * 4);
        }
        __syncthreads();
        {
            const int r2 = tid >> 2;          // hk_local
            const int c2 = (tid & 3) * 16;    // s_local chunk
            unsigned short ob[16];
            #pragma unroll
            for (int k = 0; k < 16; ++k) ob[k] = f2bf(wl[c2 + k][r2]);
            unsigned short* dst = Wt_bf + (size_t)(hk0 + r2) * FIN_ + s0 + c2;
            *(uint4*)(dst)     = *(uint4*)&ob[0];
            *(uint4*)(dst + 8) = *(uint4*)&ob[8];
        }
    } else {                              // ---- wa
        const int o    = (bid - 1216) * 256 + tid;   // 0..4095
        const int head = o >> 9;
        const int st   = (o >> 8) & 1;
        const int s    = o & 255;
        const float* wr = W + (size_t)s * (H_ * D_) + head * D_;
        const float* ar = a + head * 256 + st * 128;
        float sum = 0.f;
        #pragma unroll
        for (int d = 0; d < 128; d += 4) {
            const float4 wv = *(const float4*)(wr + d);
            const float4 av = *(const float4*)(ar + d);
            sum += wv.x * av.x + wv.y * av.y + wv.z * av.z + wv.w * av.w;
        }
        wa[s * 16 + head * 2 + st] = sum;
    }
}

// ---------------------------------------------------------------------------
// Kernel 1: bf16 MFMA GEMM, no LDS/barriers.  htT[bth][d][n] = (h @ W)^T
// grid (16,8,8) = (hk-tiles 64, n-tiles 128, bt), block 256 (4 waves).
// Wave w: hk sub-tile hk0+w*16 (B operand); A = 8 n-frags (shared, L1-hit).
// C: row = n (kgrp*4+reg, packed ushort4 stores), col = hk (row16).
// ---------------------------------------------------------------------------
__global__ __launch_bounds__(256) void k_gemm(const unsigned short* __restrict__ h_bf,
                                              const unsigned short* __restrict__ Wt_bf,
                                              unsigned short* __restrict__ htT) {
    const int bt  = blockIdx.z;
    const int n0  = blockIdx.y * 128;
    const int hk0 = blockIdx.x * 64;
    const int tid = threadIdx.x;
    const int w = tid >> 6, lane = tid & 63;
    const int row16 = lane & 15, kgrp = lane >> 4;
    const unsigned short* hb = h_bf + (size_t)bt * N_ * FIN_;
    const unsigned short* wb = Wt_bf + (size_t)(hk0 + w * 16 + row16) * FIN_;

    f32x4 acc[8];
    #pragma unroll
    for (int nt = 0; nt < 8; ++nt) acc[nt] = (f32x4){0.f, 0.f, 0.f, 0.f};

    #pragma unroll
    for (int ks = 0; ks < 8; ++ks) {
        const int k0 = ks * 32 + kgrp * 8;
        const short8 bf = *(const short8*)(wb + k0);
        #pragma unroll
        for (int nt = 0; nt < 8; ++nt) {
            const short8 af = *(const short8*)(hb + (size_t)(n0 + nt * 16 + row16) * FIN_ + k0);
            acc[nt] = __builtin_amdgcn_mfma_f32_16x16x32_bf16(af, bf, acc[nt], 0, 0, 0);
        }
    }
    const int hk   = hk0 + w * 16 + row16;
    const int head = hk >> 7;
    const int d    = hk & 127;
    unsigned short* ob = htT + ((size_t)(bt * H_ + head) * D_ + d) * N_;
    #pragma unroll
    for (int nt = 0; nt < 8; ++nt) {
        ushort4 v;
        v.x = f2bf(acc[nt][0]); v.y = f2bf(acc[nt][1]);
        v.z = f2bf(acc[nt][2]); v.w = f2bf(acc[nt][3]);
        *(ushort4*)(ob + n0 + nt * 16 + kgrp * 4) = v;
    }
}

// ---------------------------------------------------------------------------
// Kernel 2: src/tgt = h(fp32) @ wa  (exact fp32 scores).
// grid 128 blocks x 64 rows; 4 threads/row over s-quarters; shfl combine.
// ---------------------------------------------------------------------------
__global__ __launch_bounds__(256) void k_srctgt(const float* __restrict__ h,
                                                const float* __restrict__ wa,
                                                float* __restrict__ src,
                                                float* __restrict__ tgt) {
    __shared__ float was[256][16];
    const int tid = threadIdx.x;
    {   // stage wa (4096 f32)
        const int f = tid * 16;
        #pragma unroll
        for (int k = 0; k < 4; ++k)
            *(float4*)&was[f >> 4][k * 4] = *(const float4*)(wa + f + k * 4);
    }
    __syncthreads();
    const int r = tid >> 2, q = tid & 3;
    const int R = blockIdx.x * 64 + r;
    const float* hrow = h + (size_t)R * FIN_ + q * 64;
    float acc[16];
    #pragma unroll
    for (int o = 0; o < 16; ++o) acc[o] = 0.f;
    for (int k = 0; k < 64; k += 4) {
        const float4 hv = *(const float4*)(hrow + k);
        const int s = q * 64 + k;
        #pragma unroll
        for (int kk = 0; kk < 4; ++kk) {
            const float hs = (kk == 0) ? hv.x : (kk == 1) ? hv.y : (kk == 2) ? hv.z : hv.w;
            #pragma unroll
            for (int o = 0; o < 16; ++o) acc[o] += hs * was[s + kk][o];
        }
    }
    // combine 4 s-quarters: lanes r*4+q are consecutive
    #pragma unroll
    for (int o = 0; o < 16; ++o) {
        acc[o] += __shfl_xor(acc[o], 1);
        acc[o] += __shfl_xor(acc[o], 2);
    }
    // lane q writes outputs o in [q*4, q*4+4)
    const int bt = R >> 10, n = R & 1023;
    #pragma unroll
    for (int k = 0; k < 4; ++k) {
        const int o = q * 4 + k;
        const int head = o >> 1;
        float* dst = (o & 1) ? tgt : src;
        dst[((size_t)(bt * H_ + head)) * N_ + n] = acc[o];
    }
}

// ---------------------------------------------------------------------------
// Kernel 3: fused mask+softmax+PV via MFMA. No LDS, no barriers.
// grid (16,32), block 256 = 4 independent waves; wave = 16 i-rows, both b.
// 2-stage software pipeline over 32-j steps (named double buffers).
// ---------------------------------------------------------------------------
__global__ __launch_bounds__(256, 2) void k_attn(const unsigned short* __restrict__ htT,
                                                 const float* __restrict__ src,
                                                 const float* __restrict__ tgt,
                                                 const uint32_t* __restrict__ adjbits,
                                                 float* __restrict__ out) {
    const int th  = blockIdx.y;
    const int i0  = blockIdx.x * 64;
    const int tid = threadIdx.x;
    const int w = tid >> 6, lane = tid & 63;
    const int row16 = lane & 15, kgrp = lane >> 4, jrel = kgrp * 8;
    const int i = i0 + w * 16 + row16;
    const int bth0 = th, bth1 = T_ * H_ + th;
    const unsigned short* hb0 = htT + (size_t)bth0 * D_ * N_;
    const unsigned short* hb1 = htT + (size_t)bth1 * D_ * N_;
    const float* tg0 = tgt + (size_t)bth0 * N_;
    const float* tg1 = tgt + (size_t)bth1 * N_;
    const float s0 = src[(size_t)bth0 * N_ + i];
    const float s1 = src[(size_t)bth1 * N_ + i];
    const uint32_t* arow = adjbits + (size_t)i * (N_ / 32);

    f32x4 acc0[8], acc1[8];
    #pragma unroll
    for (int nt = 0; nt < 8; ++nt) {
        acc0[nt] = (f32x4){0.f, 0.f, 0.f, 0.f};
        acc1[nt] = (f32x4){0.f, 0.f, 0.f, 0.f};
    }
    float den0 = 0.f, den1 = 0.f;

#define LOADF(FB0, FB1, ADJW, TQ0L, TQ0H, TQ1L, TQ1H, J0)                          \
    {                                                                              \
        const int jj = (J0);                                                       \
        ADJW = arow[jj >> 5];                                                      \
        TQ0L = *(const float4*)(tg0 + jj + jrel);                                  \
        TQ0H = *(const float4*)(tg0 + jj + jrel + 4);                              \
        TQ1L = *(const float4*)(tg1 + jj + jrel);                                  \
        TQ1H = *(const float4*)(tg1 + jj + jrel + 4);                              \
        _Pragma("unroll")                                                          \
        for (int nt = 0; nt < 8; ++nt) {                                           \
            FB0[nt] = *(const short8*)(hb0 + (size_t)(nt * 16 + row16) * N_ + jj + jrel); \
            FB1[nt] = *(const short8*)(hb1 + (size_t)(nt * 16 + row16) * N_ + jj + jrel); \
        }                                                                          \
    }

#define SCORES(AF, ADJW, TQL, TQH, SRCV, DEN)                                      \
    {                                                                              \
        const float tj[8] = {TQL.x, TQL.y, TQL.z, TQL.w, TQH.x, TQH.y, TQH.z, TQH.w}; \
        _Pragma("unroll")                                                          \
        for (int e = 0; e < 8; ++e) {                                              \
            float ev = SRCV + tj[e];                                               \
            ev = fmaxf(ev, SLOPE_ * ev);                                           \
            const float wv = ((ADJW >> (jrel + e)) & 1u) ? __expf(ev) : 0.f;       \
            DEN += wv;                                                             \
            AF[e] = (short)f2bf(wv);                                               \
        }                                                                          \
    }

#define PROC(FB0, FB1, ADJW, TQ0L, TQ0H, TQ1L, TQ1H)                               \
    {                                                                              \
        short8 af0, af1;                                                           \
        SCORES(af0, ADJW, TQ0L, TQ0H, s0, den0)                                    \
        SCORES(af1, ADJW, TQ1L, TQ1H, s1, den1)                                    \
        _Pragma("unroll")                                                          \
        for (int nt = 0; nt < 8; ++nt) {                                           \
            acc0[nt] = __builtin_amdgcn_mfma_f32_16x16x32_bf16(af0, FB0[nt], acc0[nt], 0, 0, 0); \
            acc1[nt] = __builtin_amdgcn_mfma_f32_16x16x32_bf16(af1, FB1[nt], acc1[nt], 0, 0, 0); \
        }                                                                          \
    }

    short8 fa0[8], fa1[8], fb0[8], fb1[8];
    uint32_t adjA, adjB;
    float4 tA0l, tA0h, tA1l, tA1h, tB0l, tB0h, tB1l, tB1h;

    LOADF(fa0, fa1, adjA, tA0l, tA0h, tA1l, tA1h, 0)
    for (int j0 = 0; j0 < N_; j0 += 64) {
        LOADF(fb0, fb1, adjB, tB0l, tB0h, tB1l, tB1h, j0 + 32)
        PROC(fa0, fa1, adjA, tA0l, tA0h, tA1l, tA1h)
        LOADF(fa0, fa1, adjA, tA0l, tA0h, tA1l, tA1h, (j0 + 64) & (N_ - 1))
        PROC(fb0, fb1, adjB, tB0l, tB0h, tB1l, tB1h)
    }
#undef LOADF
#undef SCORES
#undef PROC

    den0 += __shfl_xor(den0, 16); den0 += __shfl_xor(den0, 32);
    den1 += __shfl_xor(den1, 16); den1 += __shfl_xor(den1, 32);
    const float iv0 = 1.0f / den0;
    const float iv1 = 1.0f / den1;
    float d0r[4], d1r[4];
    #pragma unroll
    for (int reg = 0; reg < 4; ++reg) {
        d0r[reg] = __shfl(iv0, kgrp * 4 + reg);
        d1r[reg] = __shfl(iv1, kgrp * 4 + reg);
    }
    #pragma unroll
    for (int nt = 0; nt < 8; ++nt)
        #pragma unroll
        for (int reg = 0; reg < 4; ++reg) {
            const int irow = i0 + w * 16 + kgrp * 4 + reg;
            const int d    = nt * 16 + row16;
            out[((size_t)th * N_ + irow) * D_ + d] =
                0.5f * (acc0[nt][reg] * d0r[reg] + acc1[nt][reg] * d1r[reg]);
        }
}

extern "C" void kernel_launch(void* const* d_in, const int* in_sizes, int n_in,
                              void* d_out, int out_size, void* d_ws, size_t ws_size,
                              hipStream_t stream) {
    const float* h   = (const float*)d_in[0];
    const int*   adj = (const int*)d_in[1];
    const float* W   = (const float*)d_in[2];
    const float* a   = (const float*)d_in[3];
    float* out = (float*)d_out;

    // ws: htT 16.78MB | src 256KB | tgt 256KB | adjbits 128KB | h_bf 4.2MB |
    //     Wt_bf 512KB | wa 16KB   (total ~22.1MB)
    char* p = (char*)d_ws;
    unsigned short* htT = (unsigned short*)p;  p += (size_t)B_ * T_ * H_ * D_ * N_ * 2;
    float* src = (float*)p;                    p += (size_t)B_ * T_ * H_ * N_ * 4;
    float* tgt = (float*)p;                    p += (size_t)B_ * T_ * H_ * N_ * 4;
    uint32_t* adjbits = (uint32_t*)p;          p += (size_t)N_ * N_ / 32 * 4;
    unsigned short* h_bf = (unsigned short*)p; p += (size_t)B_ * T_ * N_ * FIN_ * 2;
    unsigned short* Wt_bf = (unsigned short*)p;p += (size_t)(H_ * D_) * FIN_ * 2;
    float* wa = (float*)p;

    k_prep<<<dim3(1232), dim3(256), 0, stream>>>(h, adj, W, a, h_bf, Wt_bf, adjbits, wa);
    k_gemm<<<dim3(16, 8, 8), dim3(256), 0, stream>>>(h_bf, Wt_bf, htT);
    k_srctgt<<<dim3(128), dim3(256), 0, stream>>>(h, wa, src, tgt);
    k_attn<<<dim3(16, 32), dim3(256), 0, stream>>>(htT, src, tgt, adjbits, out);
}

// Round 4
// 105.793 us; speedup vs baseline: 2.2172x; 2.2172x over previous
//
#include <hip/hip_runtime.h>
#include <cstddef>
#include <cstdint>

#define B_ 2
#define T_ 4
#define N_ 1024
#define FIN_ 256
#define H_ 8
#define D_ 128
#define L2E_ 1.4426950408889634f

typedef __attribute__((ext_vector_type(8))) short short8;
typedef __attribute__((ext_vector_type(4))) float f32x4;

#define MFMA16(A, B, C) __builtin_amdgcn_mfma_f32_16x16x32_bf16((A), (B), (C), 0, 0, 0)

__device__ __forceinline__ unsigned short f2bf(float f) {
    uint32_t u = __float_as_uint(f);
    uint32_t r = (u + 0x7fffu + ((u >> 16) & 1u)) >> 16;   // RNE
    return (unsigned short)r;
}

__device__ __forceinline__ uint32_t cvt_pk_bf16(float lo, float hi) {
    uint32_t r;
    asm volatile("v_cvt_pk_bf16_f32 %0, %1, %2" : "=v"(r) : "v"(lo), "v"(hi));
    return r;
}

// async global->LDS, 16B per lane, linear dest (base + lane*16)
__device__ __forceinline__ void load_lds16(const unsigned short* g, unsigned short* l) {
    __builtin_amdgcn_global_load_lds(
        (const __attribute__((address_space(1))) uint32_t*)g,
        (__attribute__((address_space(3))) uint32_t*)l, 16, 0, 0);
}

// ---------------------------------------------------------------------------
// Kernel 0 (prep, region-dispatched by blockIdx.x):
//   [0,128)      : pack adj -> adjbits
//   [128,1152)   : h fp32 -> h_bf bf16
//   [1152,1216)  : W [s][hk] -> Wt_bf [hk][s] bf16
//   [1216,1232)  : wa[s][head*2+st] = sum_d W[s][head*128+d]*a[head*256+st*128+d]
// ---------------------------------------------------------------------------
__global__ __launch_bounds__(256) void k_prep(const float* __restrict__ h,
                                              const int* __restrict__ adj,
                                              const float* __restrict__ W,
                                              const float* __restrict__ a,
                                              unsigned short* __restrict__ h_bf,
                                              unsigned short* __restrict__ Wt_bf,
                                              uint32_t* __restrict__ adjbits,
                                              float* __restrict__ wa) {
    __shared__ float wl[64][68];
    const int bid = blockIdx.x, tid = threadIdx.x;
    if (bid < 128) {                      // ---- adj pack
        const int w = bid * 256 + tid;
        const int i = w >> 5, jw = w & 31;
        const int4* p = (const int4*)(adj + (size_t)i * N_ + jw * 32);
        uint32_t bits = 0;
        #pragma unroll
        for (int q = 0; q < 8; ++q) {
            const int4 v = p[q];
            bits |= (uint32_t)(v.x > 0) << (q * 4 + 0);
            bits |= (uint32_t)(v.y > 0) << (q * 4 + 1);
            bits |= (uint32_t)(v.z > 0) << (q * 4 + 2);
            bits |= (uint32_t)(v.w > 0) << (q * 4 + 3);
        }
        adjbits[w] = bits;
    } else if (bid < 1152) {              // ---- h -> bf16
        const size_t base = ((size_t)(bid - 128) * 256 + tid) * 8;
        const float4 v0 = *(const float4*)(h + base);
        const float4 v1 = *(const float4*)(h + base + 4);
        unsigned short ob[8];
        ob[0] = f2bf(v0.x); ob[1] = f2bf(v0.y); ob[2] = f2bf(v0.z); ob[3] = f2bf(v0.w);
        ob[4] = f2bf(v1.x); ob[5] = f2bf(v1.y); ob[6] = f2bf(v1.z); ob[7] = f2bf(v1.w);
        *(uint4*)(h_bf + base) = *(uint4*)&ob[0];
    } else if (bid < 1216) {              // ---- W transpose -> bf16
        const int tb  = bid - 1152;
        const int hk0 = (tb >> 2) * 64;
        const int s0  = (tb & 3) * 64;
        {
            const int r  = tid >> 2;
            const int c0 = (tid & 3) * 16;
            #pragma unroll
            for (int k = 0; k < 4; ++k)
                *(float4*)&wl[r][c0 + k * 4] =
                    *(const float4*)(W + (size_t)(s0 + r) * (H_ * D_) + hk0 + c0 + k * 4);
        }
        __syncthreads();
        {
            const int r2 = tid >> 2;
            const int c2 = (tid & 3) * 16;
            unsigned short ob[16];
            #pragma unroll
            for (int k = 0; k < 16; ++k) ob[k] = f2bf(wl[c2 + k][r2]);
            unsigned short* dst = Wt_bf + (size_t)(hk0 + r2) * FIN_ + s0 + c2;
            *(uint4*)(dst)     = *(uint4*)&ob[0];
            *(uint4*)(dst + 8) = *(uint4*)&ob[8];
        }
    } else {                              // ---- wa
        const int o    = (bid - 1216) * 256 + tid;
        const int head = o >> 9;
        const int st   = (o >> 8) & 1;
        const int s    = o & 255;
        const float* wr = W + (size_t)s * (H_ * D_) + head * D_;
        const float* ar = a + head * 256 + st * 128;
        float sum = 0.f;
        #pragma unroll
        for (int d = 0; d < 128; d += 4) {
            const float4 wv = *(const float4*)(wr + d);
            const float4 av = *(const float4*)(ar + d);
            sum += wv.x * av.x + wv.y * av.y + wv.z * av.z + wv.w * av.w;
        }
        wa[s * 16 + head * 2 + st] = sum;
    }
}

// ---------------------------------------------------------------------------
// Kernel 1 (merged): [0,1024) bf16 MFMA GEMM -> htT ; [1024,1152) prescaled
// score projections s1,s2,t1,t2 = (h @ wa) * {L2E, 0.2*L2E}.
// ---------------------------------------------------------------------------
__global__ __launch_bounds__(256) void k_gemm_sp(const unsigned short* __restrict__ h_bf,
                                                 const unsigned short* __restrict__ Wt_bf,
                                                 const float* __restrict__ h,
                                                 const float* __restrict__ wa,
                                                 unsigned short* __restrict__ htT,
                                                 float* __restrict__ s1, float* __restrict__ s2,
                                                 float* __restrict__ t1, float* __restrict__ t2) {
    __shared__ float was[256][16];
    const int bid = blockIdx.x, tid = threadIdx.x;
    if (bid < 1024) {                     // ---- GEMM: htT[bth][d][n] = (h@W)^T bf16
        const int bt  = bid >> 7;
        const int r_  = bid & 127;
        const int n0  = (r_ >> 4) * 128;
        const int hk0 = (r_ & 15) * 64;
        const int w = tid >> 6, lane = tid & 63;
        const int row16 = lane & 15, kgrp = lane >> 4;
        const unsigned short* hb = h_bf + (size_t)bt * N_ * FIN_;
        const unsigned short* wb = Wt_bf + (size_t)(hk0 + w * 16 + row16) * FIN_;
        f32x4 acc[8];
        #pragma unroll
        for (int nt = 0; nt < 8; ++nt) acc[nt] = (f32x4){0.f, 0.f, 0.f, 0.f};
        #pragma unroll
        for (int ks = 0; ks < 8; ++ks) {
            const int k0 = ks * 32 + kgrp * 8;
            const short8 bf = *(const short8*)(wb + k0);
            #pragma unroll
            for (int nt = 0; nt < 8; ++nt) {
                const short8 af = *(const short8*)(hb + (size_t)(n0 + nt * 16 + row16) * FIN_ + k0);
                acc[nt] = MFMA16(af, bf, acc[nt]);
            }
        }
        const int hk   = hk0 + w * 16 + row16;
        const int head = hk >> 7;
        const int d    = hk & 127;
        unsigned short* ob = htT + ((size_t)(bt * H_ + head) * D_ + d) * N_;
        #pragma unroll
        for (int nt = 0; nt < 8; ++nt) {
            ushort4 v;
            v.x = f2bf(acc[nt][0]); v.y = f2bf(acc[nt][1]);
            v.z = f2bf(acc[nt][2]); v.w = f2bf(acc[nt][3]);
            *(ushort4*)(ob + n0 + nt * 16 + kgrp * 4) = v;
        }
    } else {                              // ---- prescaled src/tgt
        {
            const int f = tid * 16;
            #pragma unroll
            for (int k = 0; k < 4; ++k)
                *(float4*)&was[f >> 4][k * 4] = *(const float4*)(wa + f + k * 4);
        }
        __syncthreads();
        const int r = tid >> 2, q = tid & 3;
        const int R = (bid - 1024) * 64 + r;
        const float* hrow = h + (size_t)R * FIN_ + q * 64;
        float acc[16];
        #pragma unroll
        for (int o = 0; o < 16; ++o) acc[o] = 0.f;
        for (int k = 0; k < 64; k += 4) {
            const float4 hv = *(const float4*)(hrow + k);
            const int s = q * 64 + k;
            #pragma unroll
            for (int kk = 0; kk < 4; ++kk) {
                const float hs = (kk == 0) ? hv.x : (kk == 1) ? hv.y : (kk == 2) ? hv.z : hv.w;
                #pragma unroll
                for (int o = 0; o < 16; ++o) acc[o] += hs * was[s + kk][o];
            }
        }
        #pragma unroll
        for (int o = 0; o < 16; ++o) {
            acc[o] += __shfl_xor(acc[o], 1);
            acc[o] += __shfl_xor(acc[o], 2);
        }
        const int bt = R >> 10, n = R & 1023;
        #pragma unroll
        for (int k = 0; k < 4; ++k) {
            const int o = q * 4 + k;
            const int head = o >> 1;
            const size_t idx = ((size_t)(bt * H_ + head)) * N_ + n;
            const float v = acc[o];
            if (o & 1) { t1[idx] = v * L2E_; t2[idx] = v * (0.2f * L2E_); }
            else       { s1[idx] = v * L2E_; s2[idx] = v * (0.2f * L2E_); }
        }
    }
}

// ---------------------------------------------------------------------------
// Kernel 2: fused mask+softmax+PV via MFMA.
// grid (16, 32) = (i-tiles of 64, t*H), block 256 = 4 waves.
// wave = (isub = w>>1) i-half of 32 rows x (b = w&1). 2048 waves = 2/SIMD.
// LDS: double-buffered stage[2][2 b][128 d][32 j] bf16 (32 KB), filled by
// async global_load_lds (16B); [d][32j] rows (64B) make B-frag ds_read_b128 a
// perfect 1024B tiling -> conflict-free, no padding.
// One __syncthreads per 32-j step (T3-minimum 2-phase); stage(t+1) issued
// before compute(t). Scores: e = max(s1+t1j, s2+t2j) -> v_exp (exp2),
// mask from adjbits, pack via v_cvt_pk_bf16_f32. Denominator = extra MFMA
// with ones-column B. Cross-b mean via LDS at the end.
// ---------------------------------------------------------------------------
__global__ __launch_bounds__(256, 2) void k_attn(const unsigned short* __restrict__ htT,
                                                 const float* __restrict__ s1,
                                                 const float* __restrict__ s2,
                                                 const float* __restrict__ t1,
                                                 const float* __restrict__ t2,
                                                 const uint32_t* __restrict__ adjbits,
                                                 float* __restrict__ out) {
    __shared__ __align__(16) char smem[32768];
    unsigned short* stg = (unsigned short*)smem;   // shorts: buf*8192 + b*4096 + d*32 + j
    const int th  = blockIdx.y;
    const int i0  = blockIdx.x * 64;
    const int tid = threadIdx.x;
    const int w = tid >> 6, lane = tid & 63;
    const int b = w & 1, isub = w >> 1;
    const int row16 = lane & 15, kgrp = lane >> 4, jrel = kgrp * 8;
    const int bth = b * (T_ * H_) + th;
    const int iA = i0 + isub * 32 + row16;
    const int iB = iA + 16;
    const float s1A = s1[(size_t)bth * N_ + iA], s2A = s2[(size_t)bth * N_ + iA];
    const float s1B = s1[(size_t)bth * N_ + iB], s2B = s2[(size_t)bth * N_ + iB];
    const float* t1b = t1 + (size_t)bth * N_;
    const float* t2b = t2 + (size_t)bth * N_;
    const uint32_t* adjA = adjbits + (size_t)iA * (N_ / 32);
    const uint32_t* adjB = adjbits + (size_t)iB * (N_ / 32);

    // staging: wave w fills quarter w of the 16KB tile (4 x 1KB instrs)
    const int sb  = w >> 1;                       // staged b
    const int sd0 = (w & 1) * 64 + (lane >> 2);   // staged d row
    const int sj  = (lane & 3) * 8;               // staged j offset
    const unsigned short* gstg = htT + ((size_t)(sb * (T_ * H_) + th) * D_ + sd0) * N_ + sj;
    unsigned short* lstg = stg + (size_t)w * 2048 + (size_t)lane * 8;

#define STAGE(BUF, T) {                                          \
        const unsigned short* gs = gstg + (size_t)(T) * 32;      \
        unsigned short* ls = lstg + (BUF) * 8192;                \
        load_lds16(gs,           ls);                            \
        load_lds16(gs + 16 * N_, ls + 512);                      \
        load_lds16(gs + 32 * N_, ls + 1024);                     \
        load_lds16(gs + 48 * N_, ls + 1536); }

    f32x4 acc0[8], acc1[8];
    #pragma unroll
    for (int nt = 0; nt < 8; ++nt) {
        acc0[nt] = (f32x4){0.f, 0.f, 0.f, 0.f};
        acc1[nt] = (f32x4){0.f, 0.f, 0.f, 0.f};
    }
    f32x4 dacc0 = (f32x4){0.f, 0.f, 0.f, 0.f};
    f32x4 dacc1 = (f32x4){0.f, 0.f, 0.f, 0.f};
    short8 ones8;
    {
        const short ov = (row16 == 0) ? (short)0x3F80 : (short)0;
        #pragma unroll
        for (int e = 0; e < 8; ++e) ones8[e] = ov;
    }
    const unsigned short* rdbase = stg + b * 4096 + row16 * 32 + jrel;

    STAGE(0, 0)
    __syncthreads();

    for (int t = 0; t < 32; ++t) {
        const int cur = t & 1;
        if (t < 31) STAGE(cur ^ 1, t + 1)
        // ---- scores (global loads + VALU only; overlaps in-flight stage)
        const uint32_t awA = adjA[t] >> jrel;
        const uint32_t awB = adjB[t] >> jrel;
        const float4 q1l = *(const float4*)(t1b + t * 32 + jrel);
        const float4 q1h = *(const float4*)(t1b + t * 32 + jrel + 4);
        const float4 q2l = *(const float4*)(t2b + t * 32 + jrel);
        const float4 q2h = *(const float4*)(t2b + t * 32 + jrel + 4);
        const float tj1[8] = {q1l.x, q1l.y, q1l.z, q1l.w, q1h.x, q1h.y, q1h.z, q1h.w};
        const float tj2[8] = {q2l.x, q2l.y, q2l.z, q2l.w, q2h.x, q2h.y, q2h.z, q2h.w};
        float wA[8], wB[8];
        #pragma unroll
        for (int e = 0; e < 8; ++e) {
            const float eA = fmaxf(s1A + tj1[e], s2A + tj2[e]);
            const float eB = fmaxf(s1B + tj1[e], s2B + tj2[e]);
            wA[e] = ((awA >> e) & 1u) ? exp2f(eA) : 0.f;
            wB[e] = ((awB >> e) & 1u) ? exp2f(eB) : 0.f;
        }
        short8 afA, afB;
        #pragma unroll
        for (int p = 0; p < 4; ++p) {
            ((uint32_t*)&afA)[p] = cvt_pk_bf16(wA[2 * p], wA[2 * p + 1]);
            ((uint32_t*)&afB)[p] = cvt_pk_bf16(wB[2 * p], wB[2 * p + 1]);
        }
        // ---- B frags + MFMA
        const unsigned short* rb = rdbase + cur * 8192;
        short8 bf[8];
        #pragma unroll
        for (int nt = 0; nt < 8; ++nt) bf[nt] = *(const short8*)(rb + nt * 512);
        #pragma unroll
        for (int nt = 0; nt < 8; ++nt) {
            acc0[nt] = MFMA16(afA, bf[nt], acc0[nt]);
            acc1[nt] = MFMA16(afB, bf[nt], acc1[nt]);
        }
        dacc0 = MFMA16(afA, ones8, dacc0);
        dacc1 = MFMA16(afB, ones8, dacc1);
        __syncthreads();   // all reads of cur done; stage(t+1) drained (vmcnt0)
    }
#undef STAGE

    // inverse denominators: C[r][0] lives in lane kgrp*16, reg r&3
    float iv0[4], iv1[4];
    #pragma unroll
    for (int r = 0; r < 4; ++r) {
        iv0[r] = __shfl(1.0f / dacc0[r], kgrp * 16);
        iv1[r] = __shfl(1.0f / dacc1[r], kgrp * 16);
    }

    // cross-b mean via LDS (reuse stage memory: 64 x 128 f32 = 32KB)
    float* comb = (float*)smem;
    if (b == 1) {
        #pragma unroll
        for (int nt = 0; nt < 8; ++nt)
            #pragma unroll
            for (int r = 0; r < 4; ++r) {
                const int il = isub * 32 + kgrp * 4 + r;
                const int d  = nt * 16 + row16;
                comb[il * 128 + d]        = acc0[nt][r] * iv0[r];
                comb[(il + 16) * 128 + d] = acc1[nt][r] * iv1[r];
            }
    }
    __syncthreads();
    if (b == 0) {
        #pragma unroll
        for (int nt = 0; nt < 8; ++nt)
            #pragma unroll
            for (int r = 0; r < 4; ++r) {
                const int il = isub * 32 + kgrp * 4 + r;
                const int d  = nt * 16 + row16;
                out[((size_t)th * N_ + i0 + il) * D_ + d] =
                    0.5f * (acc0[nt][r] * iv0[r] + comb[il * 128 + d]);
                out[((size_t)th * N_ + i0 + il + 16) * D_ + d] =
                    0.5f * (acc1[nt][r] * iv1[r] + comb[(il + 16) * 128 + d]);
            }
    }
}

extern "C" void kernel_launch(void* const* d_in, const int* in_sizes, int n_in,
                              void* d_out, int out_size, void* d_ws, size_t ws_size,
                              hipStream_t stream) {
    const float* h   = (const float*)d_in[0];
    const int*   adj = (const int*)d_in[1];
    const float* W   = (const float*)d_in[2];
    const float* a   = (const float*)d_in[3];
    float* out = (float*)d_out;

    // ws: htT 16.78MB | s1,s2,t1,t2 4x256KB | adjbits 128KB | h_bf 4.2MB |
    //     Wt_bf 512KB | wa 16KB  (~22.7MB)
    char* p = (char*)d_ws;
    unsigned short* htT = (unsigned short*)p;  p += (size_t)B_ * T_ * H_ * D_ * N_ * 2;
    float* s1 = (float*)p;                     p += (size_t)B_ * T_ * H_ * N_ * 4;
    float* s2 = (float*)p;                     p += (size_t)B_ * T_ * H_ * N_ * 4;
    float* t1 = (float*)p;                     p += (size_t)B_ * T_ * H_ * N_ * 4;
    float* t2 = (float*)p;                     p += (size_t)B_ * T_ * H_ * N_ * 4;
    uint32_t* adjbits = (uint32_t*)p;          p += (size_t)N_ * N_ / 32 * 4;
    unsigned short* h_bf = (unsigned short*)p; p += (size_t)B_ * T_ * N_ * FIN_ * 2;
    unsigned short* Wt_bf = (unsigned short*)p;p += (size_t)(H_ * D_) * FIN_ * 2;
    float* wa = (float*)p;

    k_prep<<<dim3(1232), dim3(256), 0, stream>>>(h, adj, W, a, h_bf, Wt_bf, adjbits, wa);
    k_gemm_sp<<<dim3(1152), dim3(256), 0, stream>>>(h_bf, Wt_bf, h, wa, htT, s1, s2, t1, t2);
    k_attn<<<dim3(16, 32), dim3(256), 0, stream>>>(htT, s1, s2, t1, t2, adjbits, out);
}

// Round 5
// 105.325 us; speedup vs baseline: 2.2271x; 1.0044x over previous
//
#include <hip/hip_runtime.h>
#include <cstddef>
#include <cstdint>

#define B_ 2
#define T_ 4
#define N_ 1024
#define FIN_ 256
#define H_ 8
#define D_ 128
#define L2E_ 1.4426950408889634f

typedef __attribute__((ext_vector_type(8))) short short8;
typedef __attribute__((ext_vector_type(4))) float f32x4;
typedef __attribute__((ext_vector_type(2))) float f32x2;

#define MFMA16(A, B, C) __builtin_amdgcn_mfma_f32_16x16x32_bf16((A), (B), (C), 0, 0, 0)

__device__ __forceinline__ unsigned short f2bf(float f) {
    uint32_t u = __float_as_uint(f);
    uint32_t r = (u + 0x7fffu + ((u >> 16) & 1u)) >> 16;   // RNE
    return (unsigned short)r;
}

__device__ __forceinline__ uint32_t cvt_pk_bf16(float lo, float hi) {
    uint32_t r;
    asm volatile("v_cvt_pk_bf16_f32 %0, %1, %2" : "=v"(r) : "v"(lo), "v"(hi));
    return r;
}

// async global->LDS, 16B per lane (dest = wave base + lane*16)
__device__ __forceinline__ void load_lds16(const unsigned short* g, unsigned short* l) {
    __builtin_amdgcn_global_load_lds(
        (const __attribute__((address_space(1))) uint32_t*)g,
        (__attribute__((address_space(3))) uint32_t*)l, 16, 0, 0);
}

// ---------------------------------------------------------------------------
// Kernel 0 (prep, region-dispatched):
//  [0,512)   : adjm pair-mask table: adjm[i][j/2] u32 =
//              (adj[i][2p]>0 ? 0xFFFF : 0) | (adj[i][2p+1]>0 ? 0xFFFF0000 : 0)
//  [512,576) : W [s][hk] -> Wt_bf [hk][s] bf16 (LDS transpose)
//  [576,592) : wa[s][head*2+st] = sum_d W[s][head*128+d]*a[head*256+st*128+d]
// ---------------------------------------------------------------------------
__global__ __launch_bounds__(256) void k_prep(const int* __restrict__ adj,
                                              const float* __restrict__ W,
                                              const float* __restrict__ a,
                                              unsigned short* __restrict__ Wt_bf,
                                              uint32_t* __restrict__ adjm,
                                              float* __restrict__ wa) {
    __shared__ float wl[64][68];
    const int bid = blockIdx.x, tid = threadIdx.x;
    if (bid < 512) {                      // ---- adjm
        const int w0 = (bid * 256 + tid) * 4;     // word index, 4 words/thread
        const int4 p0 = *(const int4*)(adj + (size_t)w0 * 2);
        const int4 p1 = *(const int4*)(adj + (size_t)w0 * 2 + 4);
        uint4 m;
        m.x = (p0.x > 0 ? 0xFFFFu : 0u) | (p0.y > 0 ? 0xFFFF0000u : 0u);
        m.y = (p0.z > 0 ? 0xFFFFu : 0u) | (p0.w > 0 ? 0xFFFF0000u : 0u);
        m.z = (p1.x > 0 ? 0xFFFFu : 0u) | (p1.y > 0 ? 0xFFFF0000u : 0u);
        m.w = (p1.z > 0 ? 0xFFFFu : 0u) | (p1.w > 0 ? 0xFFFF0000u : 0u);
        *(uint4*)(adjm + w0) = m;
    } else if (bid < 576) {               // ---- W transpose -> bf16
        const int tb  = bid - 512;
        const int hk0 = (tb >> 2) * 64;
        const int s0  = (tb & 3) * 64;
        {
            const int r  = tid >> 2;
            const int c0 = (tid & 3) * 16;
            #pragma unroll
            for (int k = 0; k < 4; ++k)
                *(float4*)&wl[r][c0 + k * 4] =
                    *(const float4*)(W + (size_t)(s0 + r) * (H_ * D_) + hk0 + c0 + k * 4);
        }
        __syncthreads();
        {
            const int r2 = tid >> 2;
            const int c2 = (tid & 3) * 16;
            unsigned short ob[16];
            #pragma unroll
            for (int k = 0; k < 16; ++k) ob[k] = f2bf(wl[c2 + k][r2]);
            unsigned short* dst = Wt_bf + (size_t)(hk0 + r2) * FIN_ + s0 + c2;
            *(uint4*)(dst)     = *(uint4*)&ob[0];
            *(uint4*)(dst + 8) = *(uint4*)&ob[8];
        }
    } else {                              // ---- wa
        const int o    = (bid - 576) * 256 + tid;
        const int head = o >> 9;
        const int st   = (o >> 8) & 1;
        const int s    = o & 255;
        const float* wr = W + (size_t)s * (H_ * D_) + head * D_;
        const float* ar = a + head * 256 + st * 128;
        float sum = 0.f;
        #pragma unroll
        for (int d = 0; d < 128; d += 4) {
            const float4 wv = *(const float4*)(wr + d);
            const float4 av = *(const float4*)(ar + d);
            sum += wv.x * av.x + wv.y * av.y + wv.z * av.z + wv.w * av.w;
        }
        wa[s * 16 + head * 2 + st] = sum;
    }
}

// ---------------------------------------------------------------------------
// Kernel 1 (merged): [0,1024) LDS 2-phase bf16 MFMA GEMM -> htT[bth][d][n];
// fp32 h converted to bf16 during A-staging. [1024,1152) prescaled s1,s2,t1,t2.
// GEMM geometry: tile 128n x 64hk, BK=32, 4 waves (wave = 16 hk), 8 K-steps,
// XOR-swizzled LDS (slot ^= (row>>1)&3) on both write and read sides.
// XCD swizzle: 16 hk-tiles of one (bt,n0) group land on one XCD.
// ---------------------------------------------------------------------------
__global__ __launch_bounds__(256, 2) void k_gemm_sp(const float* __restrict__ h,
                                                    const unsigned short* __restrict__ Wt_bf,
                                                    const float* __restrict__ wa,
                                                    unsigned short* __restrict__ htT,
                                                    float* __restrict__ s1, float* __restrict__ s2,
                                                    float* __restrict__ t1, float* __restrict__ t2) {
    __shared__ __align__(16) char smem[24576];
    const int bid = blockIdx.x, tid = threadIdx.x;
    if (bid < 1024) {                     // ---- GEMM
        unsigned short* a_lds = (unsigned short*)smem;            // [2][4096]
        unsigned short* b_lds = (unsigned short*)(smem + 16384);  // [2][2048]
        // XCD-aware decode: xcd owns 8 (bt,n0) groups x 16 hk-tiles
        const int xcd  = bid & 7;
        const int slot = bid >> 3;            // 0..127
        const int gid  = xcd * 8 + (slot >> 4);   // 0..63 (bt,n0)
        const int bt   = gid >> 3;
        const int n0   = (gid & 7) * 128;
        const int hk0  = (slot & 15) * 64;
        const int w = tid >> 6, lane = tid & 63;
        const int row16 = lane & 15, kgrp = lane >> 4;
        const int kswz = (kgrp ^ ((row16 >> 1) & 3)) * 8;
        // A staging mapping (thread -> 16 fp32 of h)
        const int ar  = tid >> 1;             // 0..127 (n-local)
        const int akh = tid & 1;              // k half (16 floats)
        const int asub = ar >> 4, arow = ar & 15;
        const int ax = (arow >> 1) & 3;
        const int aslot0 = ((akh * 2) ^ ax) * 8;
        const int aslot1 = ((akh * 2 + 1) ^ ax) * 8;
        const float* ga = h + ((size_t)bt * N_ + n0 + ar) * FIN_ + akh * 16;
        unsigned short* aw_ = a_lds + asub * 512 + arow * 32;
        // B staging mapping (wave stages rows hk0+w*16..+16 via global_load_lds)
        const int brow = lane >> 2;
        const int bsb  = (lane & 3) ^ ((lane >> 3) & 3);
        const unsigned short* gb = Wt_bf + (size_t)(hk0 + w * 16 + brow) * FIN_ + bsb * 8;
        unsigned short* bw_ = b_lds + w * 512 + (size_t)lane * 8;

#define STAGE_AB(BUF, KS) {                                                    \
        const float* g = ga + (KS) * 32;                                       \
        const float4 f0 = *(const float4*)(g);                                 \
        const float4 f1 = *(const float4*)(g + 4);                             \
        const float4 f2 = *(const float4*)(g + 8);                             \
        const float4 f3 = *(const float4*)(g + 12);                            \
        uint4 o0, o1;                                                          \
        o0.x = cvt_pk_bf16(f0.x, f0.y); o0.y = cvt_pk_bf16(f0.z, f0.w);        \
        o0.z = cvt_pk_bf16(f1.x, f1.y); o0.w = cvt_pk_bf16(f1.z, f1.w);        \
        o1.x = cvt_pk_bf16(f2.x, f2.y); o1.y = cvt_pk_bf16(f2.z, f2.w);        \
        o1.z = cvt_pk_bf16(f3.x, f3.y); o1.w = cvt_pk_bf16(f3.z, f3.w);        \
        unsigned short* ad = aw_ + (BUF) * 4096;                               \
        *(uint4*)(ad + aslot0) = o0;                                           \
        *(uint4*)(ad + aslot1) = o1;                                           \
        load_lds16(gb + (KS) * 32, bw_ + (BUF) * 2048); }

        f32x4 acc[8];
        #pragma unroll
        for (int nt = 0; nt < 8; ++nt) acc[nt] = (f32x4){0.f, 0.f, 0.f, 0.f};

        STAGE_AB(0, 0)
        __syncthreads();
        for (int ks = 0; ks < 8; ++ks) {
            const int cur = ks & 1;
            if (ks < 7) STAGE_AB(cur ^ 1, ks + 1)
            const unsigned short* ab = a_lds + cur * 4096;
            const short8 bf = *(const short8*)(b_lds + cur * 2048 + w * 512 + row16 * 32 + kswz);
            __builtin_amdgcn_s_setprio(1);
            #pragma unroll
            for (int nt = 0; nt < 8; ++nt) {
                const short8 af = *(const short8*)(ab + nt * 512 + row16 * 32 + kswz);
                acc[nt] = MFMA16(af, bf, acc[nt]);
            }
            __builtin_amdgcn_s_setprio(0);
            __syncthreads();
        }
#undef STAGE_AB
        const int hk   = hk0 + w * 16 + row16;
        const int head = hk >> 7;
        const int d    = hk & 127;
        unsigned short* ob = htT + ((size_t)(bt * H_ + head) * D_ + d) * N_;
        #pragma unroll
        for (int nt = 0; nt < 8; ++nt) {
            ushort4 v;
            v.x = f2bf(acc[nt][0]); v.y = f2bf(acc[nt][1]);
            v.z = f2bf(acc[nt][2]); v.w = f2bf(acc[nt][3]);
            *(ushort4*)(ob + n0 + nt * 16 + kgrp * 4) = v;
        }
    } else {                              // ---- prescaled src/tgt projections
        float (*was)[16] = (float(*)[16])smem;
        {
            const int f = tid * 16;
            #pragma unroll
            for (int k = 0; k < 4; ++k)
                *(float4*)&was[f >> 4][k * 4] = *(const float4*)(wa + f + k * 4);
        }
        __syncthreads();
        const int r = tid >> 2, q = tid & 3;
        const int R = (bid - 1024) * 64 + r;
        const float* hrow = h + (size_t)R * FIN_ + q * 64;
        float acc[16];
        #pragma unroll
        for (int o = 0; o < 16; ++o) acc[o] = 0.f;
        for (int k = 0; k < 64; k += 4) {
            const float4 hv = *(const float4*)(hrow + k);
            const int s = q * 64 + k;
            #pragma unroll
            for (int kk = 0; kk < 4; ++kk) {
                const float hs = (kk == 0) ? hv.x : (kk == 1) ? hv.y : (kk == 2) ? hv.z : hv.w;
                #pragma unroll
                for (int o = 0; o < 16; ++o) acc[o] += hs * was[s + kk][o];
            }
        }
        #pragma unroll
        for (int o = 0; o < 16; ++o) {
            acc[o] += __shfl_xor(acc[o], 1);
            acc[o] += __shfl_xor(acc[o], 2);
        }
        const int bt = R >> 10, n = R & 1023;
        #pragma unroll
        for (int k = 0; k < 4; ++k) {
            const int o = q * 4 + k;
            const int head = o >> 1;
            const size_t idx = ((size_t)(bt * H_ + head)) * N_ + n;
            const float v = acc[o];
            if (o & 1) { t1[idx] = v * L2E_; t2[idx] = v * (0.2f * L2E_); }
            else       { s1[idx] = v * L2E_; s2[idx] = v * (0.2f * L2E_); }
        }
    }
}

// ---------------------------------------------------------------------------
// Kernel 2: fused mask+softmax+PV via MFMA. 1D grid 512, XCD-swizzled
// (16 i-tiles of one th on one XCD). Block = 4 waves = (isub,b); wave owns
// 32 i-rows x one b. Double-buffered LDS stage[2][2 b][128 d][32 j] bf16,
// XOR-swizzled via pre-swizzled global_load_lds source + swizzled ds_read.
// Scores: f32x2 pk adds, exp2, pair-mask AND after cvt_pk. Denominator =
// ones-column MFMA. One barrier per 32-j step.
// ---------------------------------------------------------------------------
__global__ __launch_bounds__(256, 2) void k_attn(const unsigned short* __restrict__ htT,
                                                 const float* __restrict__ s1,
                                                 const float* __restrict__ s2,
                                                 const float* __restrict__ t1,
                                                 const float* __restrict__ t2,
                                                 const uint32_t* __restrict__ adjm,
                                                 float* __restrict__ out) {
    __shared__ __align__(16) char smem[32768];
    unsigned short* stg = (unsigned short*)smem;
    // XCD decode: th = xcd*4 + (slot>>4), i-tile = slot&15
    const int xcd  = blockIdx.x & 7;
    const int slot = blockIdx.x >> 3;
    const int th   = xcd * 4 + (slot >> 4);
    const int i0   = (slot & 15) * 64;
    const int tid = threadIdx.x;
    const int w = tid >> 6, lane = tid & 63;
    const int b = w & 1, isub = w >> 1;
    const int row16 = lane & 15, kgrp = lane >> 4, jrel = kgrp * 8;
    const int kswz = (kgrp ^ ((row16 >> 1) & 3)) * 8;
    const int bth = b * (T_ * H_) + th;
    const int iA = i0 + isub * 32 + row16;
    const int iB = iA + 16;
    const float s1A = s1[(size_t)bth * N_ + iA], s2A = s2[(size_t)bth * N_ + iA];
    const float s1B = s1[(size_t)bth * N_ + iB], s2B = s2[(size_t)bth * N_ + iB];
    const f32x2 s1A2 = {s1A, s1A}, s2A2 = {s2A, s2A};
    const f32x2 s1B2 = {s1B, s1B}, s2B2 = {s2B, s2B};
    const float* t1b = t1 + (size_t)bth * N_;
    const float* t2b = t2 + (size_t)bth * N_;
    const uint32_t* amA = adjm + (size_t)iA * (N_ / 2 / 16 * 16);   // 512 words/row
    const uint32_t* amB = adjm + (size_t)iB * 512;

    // staging: wave w fills quarter w; source j pre-swizzled (slot ^ (row>>1)&3)
    const int sb  = w >> 1;
    const int sd0 = (w & 1) * 64 + (lane >> 2);
    const int sj  = ((lane & 3) ^ ((lane >> 3) & 3)) * 8;
    const unsigned short* gstg = htT + ((size_t)(sb * (T_ * H_) + th) * D_ + sd0) * N_ + sj;
    unsigned short* lstg = stg + (size_t)w * 2048 + (size_t)lane * 8;

#define STAGE(BUF, T) {                                          \
        const unsigned short* gs = gstg + (size_t)(T) * 32;      \
        unsigned short* ls = lstg + (BUF) * 8192;                \
        load_lds16(gs,           ls);                            \
        load_lds16(gs + 16 * N_, ls + 512);                      \
        load_lds16(gs + 32 * N_, ls + 1024);                     \
        load_lds16(gs + 48 * N_, ls + 1536); }

    f32x4 acc0[8], acc1[8];
    #pragma unroll
    for (int nt = 0; nt < 8; ++nt) {
        acc0[nt] = (f32x4){0.f, 0.f, 0.f, 0.f};
        acc1[nt] = (f32x4){0.f, 0.f, 0.f, 0.f};
    }
    f32x4 dacc0 = (f32x4){0.f, 0.f, 0.f, 0.f};
    f32x4 dacc1 = (f32x4){0.f, 0.f, 0.f, 0.f};
    short8 ones8;
    {
        const short ov = (row16 == 0) ? (short)0x3F80 : (short)0;
        #pragma unroll
        for (int e = 0; e < 8; ++e) ones8[e] = ov;
    }
    const unsigned short* rdbase = stg + b * 4096 + row16 * 32 + kswz;

    STAGE(0, 0)
    __syncthreads();

    for (int t = 0; t < 32; ++t) {
        const int cur = t & 1;
        if (t < 31) STAGE(cur ^ 1, t + 1)
        // ---- scores -> masked packed bf16 weights
        const uint4 mAv = *(const uint4*)(amA + t * 16 + kgrp * 4);
        const uint4 mBv = *(const uint4*)(amB + t * 16 + kgrp * 4);
        const uint32_t mAw[4] = {mAv.x, mAv.y, mAv.z, mAv.w};
        const uint32_t mBw[4] = {mBv.x, mBv.y, mBv.z, mBv.w};
        const f32x2* q1 = (const f32x2*)(t1b + t * 32 + jrel);
        const f32x2* q2 = (const f32x2*)(t2b + t * 32 + jrel);
        short8 afA, afB;
        #pragma unroll
        for (int p = 0; p < 4; ++p) {
            const f32x2 tq1 = q1[p], tq2 = q2[p];
            const f32x2 a1A = s1A2 + tq1;
            const f32x2 a2A = s2A2 + tq2;
            const f32x2 a1B = s1B2 + tq1;
            const f32x2 a2B = s2B2 + tq2;
            const float wA0 = exp2f(fmaxf(a1A[0], a2A[0]));
            const float wA1 = exp2f(fmaxf(a1A[1], a2A[1]));
            const float wB0 = exp2f(fmaxf(a1B[0], a2B[0]));
            const float wB1 = exp2f(fmaxf(a1B[1], a2B[1]));
            ((uint32_t*)&afA)[p] = cvt_pk_bf16(wA0, wA1) & mAw[p];
            ((uint32_t*)&afB)[p] = cvt_pk_bf16(wB0, wB1) & mBw[p];
        }
        // ---- B frags + MFMA
        const unsigned short* rb = rdbase + cur * 8192;
        short8 bf[8];
        #pragma unroll
        for (int nt = 0; nt < 8; ++nt) bf[nt] = *(const short8*)(rb + nt * 512);
        __builtin_amdgcn_s_setprio(1);
        #pragma unroll
        for (int nt = 0; nt < 8; ++nt) {
            acc0[nt] = MFMA16(afA, bf[nt], acc0[nt]);
            acc1[nt] = MFMA16(afB, bf[nt], acc1[nt]);
        }
        dacc0 = MFMA16(afA, ones8, dacc0);
        dacc1 = MFMA16(afB, ones8, dacc1);
        __builtin_amdgcn_s_setprio(0);
        __syncthreads();
    }
#undef STAGE

    // inverse denominators: C[r][0] lives in lane kgrp*16, reg r
    float iv0[4], iv1[4];
    #pragma unroll
    for (int r = 0; r < 4; ++r) {
        iv0[r] = __shfl(1.0f / dacc0[r], kgrp * 16);
        iv1[r] = __shfl(1.0f / dacc1[r], kgrp * 16);
    }

    // cross-b mean via LDS (reuse stage memory: 64 x 128 f32)
    float* comb = (float*)smem;
    if (b == 1) {
        #pragma unroll
        for (int nt = 0; nt < 8; ++nt)
            #pragma unroll
            for (int r = 0; r < 4; ++r) {
                const int il = isub * 32 + kgrp * 4 + r;
                const int d  = nt * 16 + row16;
                comb[il * 128 + d]        = acc0[nt][r] * iv0[r];
                comb[(il + 16) * 128 + d] = acc1[nt][r] * iv1[r];
            }
    }
    __syncthreads();
    if (b == 0) {
        #pragma unroll
        for (int nt = 0; nt < 8; ++nt)
            #pragma unroll
            for (int r = 0; r < 4; ++r) {
                const int il = isub * 32 + kgrp * 4 + r;
                const int d  = nt * 16 + row16;
                out[((size_t)th * N_ + i0 + il) * D_ + d] =
                    0.5f * (acc0[nt][r] * iv0[r] + comb[il * 128 + d]);
                out[((size_t)th * N_ + i0 + il + 16) * D_ + d] =
                    0.5f * (acc1[nt][r] * iv1[r] + comb[(il + 16) * 128 + d]);
            }
    }
}

extern "C" void kernel_launch(void* const* d_in, const int* in_sizes, int n_in,
                              void* d_out, int out_size, void* d_ws, size_t ws_size,
                              hipStream_t stream) {
    const float* h   = (const float*)d_in[0];
    const int*   adj = (const int*)d_in[1];
    const float* W   = (const float*)d_in[2];
    const float* a   = (const float*)d_in[3];
    float* out = (float*)d_out;

    // ws: htT 16.78MB | s1,s2,t1,t2 4x256KB | adjm 2MB | Wt_bf 512KB | wa 16KB
    char* p = (char*)d_ws;
    unsigned short* htT = (unsigned short*)p;  p += (size_t)B_ * T_ * H_ * D_ * N_ * 2;
    float* s1 = (float*)p;                     p += (size_t)B_ * T_ * H_ * N_ * 4;
    float* s2 = (float*)p;                     p += (size_t)B_ * T_ * H_ * N_ * 4;
    float* t1 = (float*)p;                     p += (size_t)B_ * T_ * H_ * N_ * 4;
    float* t2 = (float*)p;                     p += (size_t)B_ * T_ * H_ * N_ * 4;
    uint32_t* adjm = (uint32_t*)p;             p += (size_t)N_ * N_ / 2 * 4;
    unsigned short* Wt_bf = (unsigned short*)p;p += (size_t)(H_ * D_) * FIN_ * 2;
    float* wa = (float*)p;

    k_prep<<<dim3(592), dim3(256), 0, stream>>>(adj, W, a, Wt_bf, adjm, wa);
    k_gemm_sp<<<dim3(1152), dim3(256), 0, stream>>>(h, Wt_bf, wa, htT, s1, s2, t1, t2);
    k_attn<<<dim3(512), dim3(256), 0, stream>>>(htT, s1, s2, t1, t2, adjm, out);
}

// Round 6
// 90.918 us; speedup vs baseline: 2.5799x; 1.1585x over previous
//
#include <hip/hip_runtime.h>
#include <cstddef>
#include <cstdint>

#define B_ 2
#define T_ 4
#define N_ 1024
#define FIN_ 256
#define H_ 8
#define D_ 128
#define L2E_ 1.4426950408889634f

typedef __attribute__((ext_vector_type(8))) short short8;
typedef __attribute__((ext_vector_type(4))) float f32x4;

#define MFMA16(A, B, C) __builtin_amdgcn_mfma_f32_16x16x32_bf16((A), (B), (C), 0, 0, 0)

__device__ __forceinline__ unsigned short f2bf(float f) {
    uint32_t u = __float_as_uint(f);
    uint32_t r = (u + 0x7fffu + ((u >> 16) & 1u)) >> 16;   // RNE
    return (unsigned short)r;
}

__device__ __forceinline__ uint32_t cvt_pk_bf16(float lo, float hi) {
    uint32_t r;
    asm volatile("v_cvt_pk_bf16_f32 %0, %1, %2" : "=v"(r) : "v"(lo), "v"(hi));
    return r;
}

// async global->LDS, 16B per lane (dest = wave base + lane*16)
__device__ __forceinline__ void load_lds16(const unsigned short* g, unsigned short* l) {
    __builtin_amdgcn_global_load_lds(
        (const __attribute__((address_space(1))) uint32_t*)g,
        (__attribute__((address_space(3))) uint32_t*)l, 16, 0, 0);
}

// ---------------------------------------------------------------------------
// Kernel 0 (prep, region-dispatched):
//  [0,128)   : pack adj -> adjbits (bit j of word [i][j/32])  -- 128KB table
//  [128,192) : W [s][hk] -> Wt_bf [hk][s] bf16 (LDS transpose)
//  [192,208) : wa[s][head*2+st] = sum_d W[s][head*128+d]*a[head*256+st*128+d]
// ---------------------------------------------------------------------------
__global__ __launch_bounds__(256) void k_prep(const int* __restrict__ adj,
                                              const float* __restrict__ W,
                                              const float* __restrict__ a,
                                              unsigned short* __restrict__ Wt_bf,
                                              uint32_t* __restrict__ adjbits,
                                              float* __restrict__ wa) {
    __shared__ float wl[64][68];
    const int bid = blockIdx.x, tid = threadIdx.x;
    if (bid < 128) {                      // ---- adjbits
        const int w = bid * 256 + tid;
        const int i = w >> 5, jw = w & 31;
        const int4* p = (const int4*)(adj + (size_t)i * N_ + jw * 32);
        uint32_t bits = 0;
        #pragma unroll
        for (int q = 0; q < 8; ++q) {
            const int4 v = p[q];
            bits |= (uint32_t)(v.x > 0) << (q * 4 + 0);
            bits |= (uint32_t)(v.y > 0) << (q * 4 + 1);
            bits |= (uint32_t)(v.z > 0) << (q * 4 + 2);
            bits |= (uint32_t)(v.w > 0) << (q * 4 + 3);
        }
        adjbits[w] = bits;
    } else if (bid < 192) {               // ---- W transpose -> bf16
        const int tb  = bid - 128;
        const int hk0 = (tb >> 2) * 64;
        const int s0  = (tb & 3) * 64;
        {
            const int r  = tid >> 2;
            const int c0 = (tid & 3) * 16;
            #pragma unroll
            for (int k = 0; k < 4; ++k)
                *(float4*)&wl[r][c0 + k * 4] =
                    *(const float4*)(W + (size_t)(s0 + r) * (H_ * D_) + hk0 + c0 + k * 4);
        }
        __syncthreads();
        {
            const int r2 = tid >> 2;
            const int c2 = (tid & 3) * 16;
            unsigned short ob[16];
            #pragma unroll
            for (int k = 0; k < 16; ++k) ob[k] = f2bf(wl[c2 + k][r2]);
            unsigned short* dst = Wt_bf + (size_t)(hk0 + r2) * FIN_ + s0 + c2;
            *(uint4*)(dst)     = *(uint4*)&ob[0];
            *(uint4*)(dst + 8) = *(uint4*)&ob[8];
        }
    } else {                              // ---- wa
        const int o    = (bid - 192) * 256 + tid;
        const int head = o >> 9;
        const int st   = (o >> 8) & 1;
        const int s    = o & 255;
        const float* wr = W + (size_t)s * (H_ * D_) + head * D_;
        const float* ar = a + head * 256 + st * 128;
        float sum = 0.f;
        #pragma unroll
        for (int d = 0; d < 128; d += 4) {
            const float4 wv = *(const float4*)(wr + d);
            const float4 av = *(const float4*)(ar + d);
            sum += wv.x * av.x + wv.y * av.y + wv.z * av.z + wv.w * av.w;
        }
        wa[s * 16 + head * 2 + st] = sum;
    }
}

// ---------------------------------------------------------------------------
// Kernel 1 (merged): [0,1024) LDS 2-phase bf16 MFMA GEMM -> htT[bth][d][n];
// fp32 h converted to bf16 during A-staging. [1024,1152) prescaled s1,s2,t1,t2.
// (unchanged from R5 -- counter-verified -20us vs R4's no-LDS version)
// ---------------------------------------------------------------------------
__global__ __launch_bounds__(256, 2) void k_gemm_sp(const float* __restrict__ h,
                                                    const unsigned short* __restrict__ Wt_bf,
                                                    const float* __restrict__ wa,
                                                    unsigned short* __restrict__ htT,
                                                    float* __restrict__ s1, float* __restrict__ s2,
                                                    float* __restrict__ t1, float* __restrict__ t2) {
    __shared__ __align__(16) char smem[24576];
    const int bid = blockIdx.x, tid = threadIdx.x;
    if (bid < 1024) {                     // ---- GEMM
        unsigned short* a_lds = (unsigned short*)smem;            // [2][4096]
        unsigned short* b_lds = (unsigned short*)(smem + 16384);  // [2][2048]
        const int xcd  = bid & 7;
        const int slot = bid >> 3;
        const int gid  = xcd * 8 + (slot >> 4);
        const int bt   = gid >> 3;
        const int n0   = (gid & 7) * 128;
        const int hk0  = (slot & 15) * 64;
        const int w = tid >> 6, lane = tid & 63;
        const int row16 = lane & 15, kgrp = lane >> 4;
        const int kswz = (kgrp ^ ((row16 >> 1) & 3)) * 8;
        const int ar  = tid >> 1;
        const int akh = tid & 1;
        const int asub = ar >> 4, arow = ar & 15;
        const int ax = (arow >> 1) & 3;
        const int aslot0 = ((akh * 2) ^ ax) * 8;
        const int aslot1 = ((akh * 2 + 1) ^ ax) * 8;
        const float* ga = h + ((size_t)bt * N_ + n0 + ar) * FIN_ + akh * 16;
        unsigned short* aw_ = a_lds + asub * 512 + arow * 32;
        const int brow = lane >> 2;
        const int bsb  = (lane & 3) ^ ((lane >> 3) & 3);
        const unsigned short* gb = Wt_bf + (size_t)(hk0 + w * 16 + brow) * FIN_ + bsb * 8;
        unsigned short* bw_ = b_lds + w * 512 + (size_t)lane * 8;

#define STAGE_AB(BUF, KS) {                                                    \
        const float* g = ga + (KS) * 32;                                       \
        const float4 f0 = *(const float4*)(g);                                 \
        const float4 f1 = *(const float4*)(g + 4);                             \
        const float4 f2 = *(const float4*)(g + 8);                             \
        const float4 f3 = *(const float4*)(g + 12);                            \
        uint4 o0, o1;                                                          \
        o0.x = cvt_pk_bf16(f0.x, f0.y); o0.y = cvt_pk_bf16(f0.z, f0.w);        \
        o0.z = cvt_pk_bf16(f1.x, f1.y); o0.w = cvt_pk_bf16(f1.z, f1.w);        \
        o1.x = cvt_pk_bf16(f2.x, f2.y); o1.y = cvt_pk_bf16(f2.z, f2.w);        \
        o1.z = cvt_pk_bf16(f3.x, f3.y); o1.w = cvt_pk_bf16(f3.z, f3.w);        \
        unsigned short* ad = aw_ + (BUF) * 4096;                               \
        *(uint4*)(ad + aslot0) = o0;                                           \
        *(uint4*)(ad + aslot1) = o1;                                           \
        load_lds16(gb + (KS) * 32, bw_ + (BUF) * 2048); }

        f32x4 acc[8];
        #pragma unroll
        for (int nt = 0; nt < 8; ++nt) acc[nt] = (f32x4){0.f, 0.f, 0.f, 0.f};

        STAGE_AB(0, 0)
        __syncthreads();
        for (int ks = 0; ks < 8; ++ks) {
            const int cur = ks & 1;
            if (ks < 7) STAGE_AB(cur ^ 1, ks + 1)
            const unsigned short* ab = a_lds + cur * 4096;
            const short8 bf = *(const short8*)(b_lds + cur * 2048 + w * 512 + row16 * 32 + kswz);
            #pragma unroll
            for (int nt = 0; nt < 8; ++nt) {
                const short8 af = *(const short8*)(ab + nt * 512 + row16 * 32 + kswz);
                acc[nt] = MFMA16(af, bf, acc[nt]);
            }
            __syncthreads();
        }
#undef STAGE_AB
        const int hk   = hk0 + w * 16 + row16;
        const int head = hk >> 7;
        const int d    = hk & 127;
        unsigned short* ob = htT + ((size_t)(bt * H_ + head) * D_ + d) * N_;
        #pragma unroll
        for (int nt = 0; nt < 8; ++nt) {
            ushort4 v;
            v.x = f2bf(acc[nt][0]); v.y = f2bf(acc[nt][1]);
            v.z = f2bf(acc[nt][2]); v.w = f2bf(acc[nt][3]);
            *(ushort4*)(ob + n0 + nt * 16 + kgrp * 4) = v;
        }
    } else {                              // ---- prescaled src/tgt projections
        float (*was)[16] = (float(*)[16])smem;
        {
            const int f = tid * 16;
            #pragma unroll
            for (int k = 0; k < 4; ++k)
                *(float4*)&was[f >> 4][k * 4] = *(const float4*)(wa + f + k * 4);
        }
        __syncthreads();
        const int r = tid >> 2, q = tid & 3;
        const int R = (bid - 1024) * 64 + r;
        const float* hrow = h + (size_t)R * FIN_ + q * 64;
        float acc[16];
        #pragma unroll
        for (int o = 0; o < 16; ++o) acc[o] = 0.f;
        for (int k = 0; k < 64; k += 4) {
            const float4 hv = *(const float4*)(hrow + k);
            const int s = q * 64 + k;
            #pragma unroll
            for (int kk = 0; kk < 4; ++kk) {
                const float hs = (kk == 0) ? hv.x : (kk == 1) ? hv.y : (kk == 2) ? hv.z : hv.w;
                #pragma unroll
                for (int o = 0; o < 16; ++o) acc[o] += hs * was[s + kk][o];
            }
        }
        #pragma unroll
        for (int o = 0; o < 16; ++o) {
            acc[o] += __shfl_xor(acc[o], 1);
            acc[o] += __shfl_xor(acc[o], 2);
        }
        const int bt = R >> 10, n = R & 1023;
        #pragma unroll
        for (int k = 0; k < 4; ++k) {
            const int o = q * 4 + k;
            const int head = o >> 1;
            const size_t idx = ((size_t)(bt * H_ + head)) * N_ + n;
            const float v = acc[o];
            if (o & 1) { t1[idx] = v * L2E_; t2[idx] = v * (0.2f * L2E_); }
            else       { s1[idx] = v * L2E_; s2[idx] = v * (0.2f * L2E_); }
        }
    }
}

// ---------------------------------------------------------------------------
// Kernel 2: fused mask+softmax+PV via MFMA.
// grid 1024 (XCD-swizzled: 4 th x 32 i-tiles per XCD), block 256 = 4 waves.
// Block owns 32 i-rows; wave = 16 i-rows x one b (4 blocks/CU, 4 waves/SIMD).
// Double-buffered LDS stage[2][2 b][128 d][32 j] bf16, XOR-swizzled
// (pre-swizzled global_load_lds source + swizzled ds_read). R4-style adjbits
// scoring (broadcast dword mask). Denominator = ones-column MFMA. No setprio.
// ---------------------------------------------------------------------------
__global__ __launch_bounds__(256, 4) void k_attn(const unsigned short* __restrict__ htT,
                                                 const float* __restrict__ s1,
                                                 const float* __restrict__ s2,
                                                 const float* __restrict__ t1,
                                                 const float* __restrict__ t2,
                                                 const uint32_t* __restrict__ adjbits,
                                                 float* __restrict__ out) {
    __shared__ __align__(16) char smem[32768];
    unsigned short* stg = (unsigned short*)smem;
    // XCD decode: 128 consecutive-slot blocks per XCD cover 4 th x 32 i-tiles
    const int xcd  = blockIdx.x & 7;
    const int slot = blockIdx.x >> 3;
    const int th   = xcd * 4 + (slot >> 5);
    const int i0   = (slot & 31) * 32;
    const int tid = threadIdx.x;
    const int w = tid >> 6, lane = tid & 63;
    const int b = w & 1, half = w >> 1;
    const int row16 = lane & 15, kgrp = lane >> 4, jrel = kgrp * 8;
    const int kswz = (kgrp ^ ((row16 >> 1) & 3)) * 8;
    const int bth = b * (T_ * H_) + th;
    const int iA  = i0 + half * 16 + row16;
    const float s1A = s1[(size_t)bth * N_ + iA], s2A = s2[(size_t)bth * N_ + iA];
    const float* t1b = t1 + (size_t)bth * N_;
    const float* t2b = t2 + (size_t)bth * N_;
    const uint32_t* adjA = adjbits + (size_t)iA * (N_ / 32);

    // staging: wave w fills quarter w; source j pre-swizzled (slot ^ (d>>1)&3)
    const int sb  = w >> 1;
    const int sd0 = (w & 1) * 64 + (lane >> 2);
    const int sj  = ((lane & 3) ^ ((lane >> 3) & 3)) * 8;
    const unsigned short* gstg = htT + ((size_t)(sb * (T_ * H_) + th) * D_ + sd0) * N_ + sj;
    unsigned short* lstg = stg + (size_t)w * 2048 + (size_t)lane * 8;

#define STAGE(BUF, T) {                                          \
        const unsigned short* gs = gstg + (size_t)(T) * 32;      \
        unsigned short* ls = lstg + (BUF) * 8192;                \
        load_lds16(gs,           ls);                            \
        load_lds16(gs + 16 * N_, ls + 512);                      \
        load_lds16(gs + 32 * N_, ls + 1024);                     \
        load_lds16(gs + 48 * N_, ls + 1536); }

    f32x4 acc[8];
    #pragma unroll
    for (int nt = 0; nt < 8; ++nt) acc[nt] = (f32x4){0.f, 0.f, 0.f, 0.f};
    f32x4 dacc = (f32x4){0.f, 0.f, 0.f, 0.f};
    short8 ones8;
    {
        const short ov = (row16 == 0) ? (short)0x3F80 : (short)0;
        #pragma unroll
        for (int e = 0; e < 8; ++e) ones8[e] = ov;
    }
    const unsigned short* rdbase = stg + b * 4096 + row16 * 32 + kswz;

    STAGE(0, 0)
    __syncthreads();

    for (int t = 0; t < 32; ++t) {
        const int cur = t & 1;
        if (t < 31) STAGE(cur ^ 1, t + 1)
        // ---- scores -> masked packed bf16 weights (one 16-row set)
        const uint32_t aw = adjA[t] >> jrel;
        const float4 q1l = *(const float4*)(t1b + t * 32 + jrel);
        const float4 q1h = *(const float4*)(t1b + t * 32 + jrel + 4);
        const float4 q2l = *(const float4*)(t2b + t * 32 + jrel);
        const float4 q2h = *(const float4*)(t2b + t * 32 + jrel + 4);
        const float tj1[8] = {q1l.x, q1l.y, q1l.z, q1l.w, q1h.x, q1h.y, q1h.z, q1h.w};
        const float tj2[8] = {q2l.x, q2l.y, q2l.z, q2l.w, q2h.x, q2h.y, q2h.z, q2h.w};
        float wv[8];
        #pragma unroll
        for (int e = 0; e < 8; ++e) {
            const float ev = fmaxf(s1A + tj1[e], s2A + tj2[e]);
            wv[e] = ((aw >> e) & 1u) ? exp2f(ev) : 0.f;
        }
        short8 af;
        #pragma unroll
        for (int p = 0; p < 4; ++p)
            ((uint32_t*)&af)[p] = cvt_pk_bf16(wv[2 * p], wv[2 * p + 1]);
        // ---- B frags + MFMA
        const unsigned short* rb = rdbase + cur * 8192;
        short8 bf[8];
        #pragma unroll
        for (int nt = 0; nt < 8; ++nt) bf[nt] = *(const short8*)(rb + nt * 512);
        #pragma unroll
        for (int nt = 0; nt < 8; ++nt) acc[nt] = MFMA16(af, bf[nt], acc[nt]);
        dacc = MFMA16(af, ones8, dacc);
        __syncthreads();
    }
#undef STAGE

    // inverse denominators: D[row][0] is at lane kgrp*16, reg r (row=kgrp*4+r)
    float iv[4];
    #pragma unroll
    for (int r = 0; r < 4; ++r)
        iv[r] = __shfl(1.0f / dacc[r], kgrp * 16);

    // cross-b mean via LDS (reuse stage memory: 32 rows x 128 f32 = 16KB)
    float* comb = (float*)smem;
    if (b == 1) {
        #pragma unroll
        for (int nt = 0; nt < 8; ++nt)
            #pragma unroll
            for (int r = 0; r < 4; ++r) {
                const int il = half * 16 + kgrp * 4 + r;
                const int d  = nt * 16 + row16;
                comb[il * 128 + d] = acc[nt][r] * iv[r];
            }
    }
    __syncthreads();
    if (b == 0) {
        #pragma unroll
        for (int nt = 0; nt < 8; ++nt)
            #pragma unroll
            for (int r = 0; r < 4; ++r) {
                const int il = half * 16 + kgrp * 4 + r;
                const int d  = nt * 16 + row16;
                out[((size_t)th * N_ + i0 + il) * D_ + d] =
                    0.5f * (acc[nt][r] * iv[r] + comb[il * 128 + d]);
            }
    }
}

extern "C" void kernel_launch(void* const* d_in, const int* in_sizes, int n_in,
                              void* d_out, int out_size, void* d_ws, size_t ws_size,
                              hipStream_t stream) {
    const float* h   = (const float*)d_in[0];
    const int*   adj = (const int*)d_in[1];
    const float* W   = (const float*)d_in[2];
    const float* a   = (const float*)d_in[3];
    float* out = (float*)d_out;

    // ws: htT 16.78MB | s1,s2,t1,t2 4x256KB | adjbits 128KB | Wt_bf 512KB | wa 16KB
    char* p = (char*)d_ws;
    unsigned short* htT = (unsigned short*)p;  p += (size_t)B_ * T_ * H_ * D_ * N_ * 2;
    float* s1 = (float*)p;                     p += (size_t)B_ * T_ * H_ * N_ * 4;
    float* s2 = (float*)p;                     p += (size_t)B_ * T_ * H_ * N_ * 4;
    float* t1 = (float*)p;                     p += (size_t)B_ * T_ * H_ * N_ * 4;
    float* t2 = (float*)p;                     p += (size_t)B_ * T_ * H_ * N_ * 4;
    uint32_t* adjbits = (uint32_t*)p;          p += (size_t)N_ * N_ / 32 * 4;
    unsigned short* Wt_bf = (unsigned short*)p;p += (size_t)(H_ * D_) * FIN_ * 2;
    float* wa = (float*)p;

    k_prep<<<dim3(208), dim3(256), 0, stream>>>(adj, W, a, Wt_bf, adjbits, wa);
    k_gemm_sp<<<dim3(1152), dim3(256), 0, stream>>>(h, Wt_bf, wa, htT, s1, s2, t1, t2);
    k_attn<<<dim3(1024), dim3(256), 0, stream>>>(htT, s1, s2, t1, t2, adjbits, out);
}

// Round 8
// 76.968 us; speedup vs baseline: 3.0475x; 1.1812x over previous
//
#include <hip/hip_runtime.h>
#include <cstddef>
#include <cstdint>

#define B_ 2
#define T_ 4
#define N_ 1024
#define FIN_ 256
#define H_ 8
#define D_ 128
#define L2E_ 1.4426950408889634f

typedef __attribute__((ext_vector_type(8))) short short8;
typedef __attribute__((ext_vector_type(4))) float f32x4;

#define MFMA16(A, B, C) __builtin_amdgcn_mfma_f32_16x16x32_bf16((A), (B), (C), 0, 0, 0)

__device__ __forceinline__ unsigned short f2bf(float f) {
    uint32_t u = __float_as_uint(f);
    uint32_t r = (u + 0x7fffu + ((u >> 16) & 1u)) >> 16;   // RNE
    return (unsigned short)r;
}

__device__ __forceinline__ uint32_t cvt_pk_bf16(float lo, float hi) {
    uint32_t r;
    asm volatile("v_cvt_pk_bf16_f32 %0, %1, %2" : "=v"(r) : "v"(lo), "v"(hi));
    return r;
}

// raw v_exp_f32 (2^x) — avoids OCML guarded exp2f expansion
__device__ __forceinline__ float fexp2(float x) {
#if __has_builtin(__builtin_amdgcn_exp2f)
    return __builtin_amdgcn_exp2f(x);
#else
    float r;
    asm("v_exp_f32 %0, %1" : "=v"(r) : "v"(x));
    return r;
#endif
}

// async global->LDS, 16B per lane (dest = wave base + lane*16)
__device__ __forceinline__ void load_lds16(const unsigned short* g, unsigned short* l) {
    __builtin_amdgcn_global_load_lds(
        (const __attribute__((address_space(1))) uint32_t*)g,
        (__attribute__((address_space(3))) uint32_t*)l, 16, 0, 0);
}

// ---------------------------------------------------------------------------
// Kernel 0 (prep, region-dispatched):
//  [0,128)   : pack adj -> adjbits (bit j of word [i][j/32])
//  [128,192) : W [s][hk] -> Wt_bf [hk][s] bf16 (LDS transpose)
//  [192,208) : wa[s][head*2+st] = sum_d W[s][head*128+d]*a[head*256+st*128+d]
// ---------------------------------------------------------------------------
__global__ __launch_bounds__(256) void k_prep(const int* __restrict__ adj,
                                              const float* __restrict__ W,
                                              const float* __restrict__ a,
                                              unsigned short* __restrict__ Wt_bf,
                                              uint32_t* __restrict__ adjbits,
                                              float* __restrict__ wa) {
    __shared__ float wl[64][68];
    const int bid = blockIdx.x, tid = threadIdx.x;
    if (bid < 128) {                      // ---- adjbits
        const int w = bid * 256 + tid;
        const int i = w >> 5, jw = w & 31;
        const int4* p = (const int4*)(adj + (size_t)i * N_ + jw * 32);
        uint32_t bits = 0;
        #pragma unroll
        for (int q = 0; q < 8; ++q) {
            const int4 v = p[q];
            bits |= (uint32_t)(v.x > 0) << (q * 4 + 0);
            bits |= (uint32_t)(v.y > 0) << (q * 4 + 1);
            bits |= (uint32_t)(v.z > 0) << (q * 4 + 2);
            bits |= (uint32_t)(v.w > 0) << (q * 4 + 3);
        }
        adjbits[w] = bits;
    } else if (bid < 192) {               // ---- W transpose -> bf16
        const int tb  = bid - 128;
        const int hk0 = (tb >> 2) * 64;
        const int s0  = (tb & 3) * 64;
        {
            const int r  = tid >> 2;
            const int c0 = (tid & 3) * 16;
            #pragma unroll
            for (int k = 0; k < 4; ++k)
                *(float4*)&wl[r][c0 + k * 4] =
                    *(const float4*)(W + (size_t)(s0 + r) * (H_ * D_) + hk0 + c0 + k * 4);
        }
        __syncthreads();
        {
            const int r2 = tid >> 2;
            const int c2 = (tid & 3) * 16;
            unsigned short ob[16];
            #pragma unroll
            for (int k = 0; k < 16; ++k) ob[k] = f2bf(wl[c2 + k][r2]);
            unsigned short* dst = Wt_bf + (size_t)(hk0 + r2) * FIN_ + s0 + c2;
            *(uint4*)(dst)     = *(uint4*)&ob[0];
            *(uint4*)(dst + 8) = *(uint4*)&ob[8];
        }
    } else {                              // ---- wa
        const int o    = (bid - 192) * 256 + tid;
        const int head = o >> 9;
        const int st   = (o >> 8) & 1;
        const int s    = o & 255;
        const float* wr = W + (size_t)s * (H_ * D_) + head * D_;
        const float* ar = a + head * 256 + st * 128;
        float sum = 0.f;
        #pragma unroll
        for (int d = 0; d < 128; d += 4) {
            const float4 wv = *(const float4*)(wr + d);
            const float4 av = *(const float4*)(ar + d);
            sum += wv.x * av.x + wv.y * av.y + wv.z * av.z + wv.w * av.w;
        }
        wa[s * 16 + head * 2 + st] = sum;
    }
}

// ---------------------------------------------------------------------------
// Kernel 1 (merged): [0,1024) LDS 2-phase bf16 MFMA GEMM -> htT[bth][d][n];
// fp32 h converted to bf16 during A-staging. [1024,1152) prescaled s1,s2,t1,t2.
// (unchanged from R5/R6 -- counter-verified)
// ---------------------------------------------------------------------------
__global__ __launch_bounds__(256, 2) void k_gemm_sp(const float* __restrict__ h,
                                                    const unsigned short* __restrict__ Wt_bf,
                                                    const float* __restrict__ wa,
                                                    unsigned short* __restrict__ htT,
                                                    float* __restrict__ s1, float* __restrict__ s2,
                                                    float* __restrict__ t1, float* __restrict__ t2) {
    __shared__ __align__(16) char smem[24576];
    const int bid = blockIdx.x, tid = threadIdx.x;
    if (bid < 1024) {                     // ---- GEMM
        unsigned short* a_lds = (unsigned short*)smem;            // [2][4096]
        unsigned short* b_lds = (unsigned short*)(smem + 16384);  // [2][2048]
        const int xcd  = bid & 7;
        const int slot = bid >> 3;
        const int gid  = xcd * 8 + (slot >> 4);
        const int bt   = gid >> 3;
        const int n0   = (gid & 7) * 128;
        const int hk0  = (slot & 15) * 64;
        const int w = tid >> 6, lane = tid & 63;
        const int row16 = lane & 15, kgrp = lane >> 4;
        const int kswz = (kgrp ^ ((row16 >> 1) & 3)) * 8;
        const int ar  = tid >> 1;
        const int akh = tid & 1;
        const int asub = ar >> 4, arow = ar & 15;
        const int ax = (arow >> 1) & 3;
        const int aslot0 = ((akh * 2) ^ ax) * 8;
        const int aslot1 = ((akh * 2 + 1) ^ ax) * 8;
        const float* ga = h + ((size_t)bt * N_ + n0 + ar) * FIN_ + akh * 16;
        unsigned short* aw_ = a_lds + asub * 512 + arow * 32;
        const int brow = lane >> 2;
        const int bsb  = (lane & 3) ^ ((lane >> 3) & 3);
        const unsigned short* gb = Wt_bf + (size_t)(hk0 + w * 16 + brow) * FIN_ + bsb * 8;
        unsigned short* bw_ = b_lds + w * 512 + (size_t)lane * 8;

#define STAGE_AB(BUF, KS) {                                                    \
        const float* g = ga + (KS) * 32;                                       \
        const float4 f0 = *(const float4*)(g);                                 \
        const float4 f1 = *(const float4*)(g + 4);                             \
        const float4 f2 = *(const float4*)(g + 8);                             \
        const float4 f3 = *(const float4*)(g + 12);                            \
        uint4 o0, o1;                                                          \
        o0.x = cvt_pk_bf16(f0.x, f0.y); o0.y = cvt_pk_bf16(f0.z, f0.w);        \
        o0.z = cvt_pk_bf16(f1.x, f1.y); o0.w = cvt_pk_bf16(f1.z, f1.w);        \
        o1.x = cvt_pk_bf16(f2.x, f2.y); o1.y = cvt_pk_bf16(f2.z, f2.w);        \
        o1.z = cvt_pk_bf16(f3.x, f3.y); o1.w = cvt_pk_bf16(f3.z, f3.w);        \
        unsigned short* ad = aw_ + (BUF) * 4096;                               \
        *(uint4*)(ad + aslot0) = o0;                                           \
        *(uint4*)(ad + aslot1) = o1;                                           \
        load_lds16(gb + (KS) * 32, bw_ + (BUF) * 2048); }

        f32x4 acc[8];
        #pragma unroll
        for (int nt = 0; nt < 8; ++nt) acc[nt] = (f32x4){0.f, 0.f, 0.f, 0.f};

        STAGE_AB(0, 0)
        __syncthreads();
        for (int ks = 0; ks < 8; ++ks) {
            const int cur = ks & 1;
            if (ks < 7) STAGE_AB(cur ^ 1, ks + 1)
            const unsigned short* ab = a_lds + cur * 4096;
            const short8 bf = *(const short8*)(b_lds + cur * 2048 + w * 512 + row16 * 32 + kswz);
            #pragma unroll
            for (int nt = 0; nt < 8; ++nt) {
                const short8 af = *(const short8*)(ab + nt * 512 + row16 * 32 + kswz);
                acc[nt] = MFMA16(af, bf, acc[nt]);
            }
            __syncthreads();
        }
#undef STAGE_AB
        const int hk   = hk0 + w * 16 + row16;
        const int head = hk >> 7;
        const int d    = hk & 127;
        unsigned short* ob = htT + ((size_t)(bt * H_ + head) * D_ + d) * N_;
        #pragma unroll
        for (int nt = 0; nt < 8; ++nt) {
            ushort4 v;
            v.x = f2bf(acc[nt][0]); v.y = f2bf(acc[nt][1]);
            v.z = f2bf(acc[nt][2]); v.w = f2bf(acc[nt][3]);
            *(ushort4*)(ob + n0 + nt * 16 + kgrp * 4) = v;
        }
    } else {                              // ---- prescaled src/tgt projections
        float (*was)[16] = (float(*)[16])smem;
        {
            const int f = tid * 16;
            #pragma unroll
            for (int k = 0; k < 4; ++k)
                *(float4*)&was[f >> 4][k * 4] = *(const float4*)(wa + f + k * 4);
        }
        __syncthreads();
        const int r = tid >> 2, q = tid & 3;
        const int R = (bid - 1024) * 64 + r;
        const float* hrow = h + (size_t)R * FIN_ + q * 64;
        float acc[16];
        #pragma unroll
        for (int o = 0; o < 16; ++o) acc[o] = 0.f;
        for (int k = 0; k < 64; k += 4) {
            const float4 hv = *(const float4*)(hrow + k);
            const int s = q * 64 + k;
            #pragma unroll
            for (int kk = 0; kk < 4; ++kk) {
                const float hs = (kk == 0) ? hv.x : (kk == 1) ? hv.y : (kk == 2) ? hv.z : hv.w;
                #pragma unroll
                for (int o = 0; o < 16; ++o) acc[o] += hs * was[s + kk][o];
            }
        }
        #pragma unroll
        for (int o = 0; o < 16; ++o) {
            acc[o] += __shfl_xor(acc[o], 1);
            acc[o] += __shfl_xor(acc[o], 2);
        }
        const int bt = R >> 10, n = R & 1023;
        #pragma unroll
        for (int k = 0; k < 4; ++k) {
            const int o = q * 4 + k;
            const int head = o >> 1;
            const size_t idx = ((size_t)(bt * H_ + head)) * N_ + n;
            const float v = acc[o];
            if (o & 1) { t1[idx] = v * L2E_; t2[idx] = v * (0.2f * L2E_); }
            else       { s1[idx] = v * L2E_; s2[idx] = v * (0.2f * L2E_); }
        }
    }
}

// score-operand register set (statically addressed struct; rule-20 safe)
struct SC {
    float4 a1l, a1h, a2l, a2h;
    uint32_t mA, mB;
};

// ---------------------------------------------------------------------------
// Kernel 2: fused mask+softmax+PV via MFMA, 4-buffer counted-vmcnt pipeline.
// grid 512 (XCD-swizzled: 4 th x 16 i-tiles per XCD), block 256 = 4 waves.
// Block = 64 i-rows x both b; wave = (isub=w>>1) 32 i-rows (2 MFMA chains
// A=rows iA, B=rows iA+16 sharing B-frag reads) x (b=w&1).
// LDS: 4 x 16KB buffers [2 b][128 d][32 j] bf16, XOR-swizzled (pre-swizzled
// global_load_lds source + swizzled ds_read). Loop: exact vmcnt(14) (= 2
// in-flight stage tiles x 4 + 6 prefetched score loads) -> raw s_barrier ->
// stage t+3 -> prefetch scores t+1 (reg dbuf X/Y structs, 2x-unrolled) ->
// compute. Wraparound dummy stages keep the count uniform. Raw v_exp_f32.
// Denominator = ones-column MFMA. Cross-b mean via LDS comb after the loop.
// ---------------------------------------------------------------------------
__global__ __launch_bounds__(256, 2) void k_attn(const unsigned short* __restrict__ htT,
                                                 const float* __restrict__ s1,
                                                 const float* __restrict__ s2,
                                                 const float* __restrict__ t1,
                                                 const float* __restrict__ t2,
                                                 const uint32_t* __restrict__ adjbits,
                                                 float* __restrict__ out) {
    __shared__ __align__(16) char smem[65536];
    unsigned short* stg = (unsigned short*)smem;   // 4 bufs x 8192 shorts
    const int xcd  = blockIdx.x & 7;
    const int slot = blockIdx.x >> 3;
    const int th   = xcd * 4 + (slot >> 4);
    const int i0   = (slot & 15) * 64;
    const int tid = threadIdx.x;
    const int w = tid >> 6, lane = tid & 63;
    const int b = w & 1, isub = w >> 1;
    const int row16 = lane & 15, kgrp = lane >> 4, jrel = kgrp * 8;
    const int kswz = (kgrp ^ ((row16 >> 1) & 3)) * 8;
    const int bth = b * (T_ * H_) + th;
    const int iA  = i0 + isub * 32 + row16;
    const int iB  = iA + 16;
    const float s1A = s1[(size_t)bth * N_ + iA], s2A = s2[(size_t)bth * N_ + iA];
    const float s1B = s1[(size_t)bth * N_ + iB], s2B = s2[(size_t)bth * N_ + iB];
    const float* t1b = t1 + (size_t)bth * N_;
    const float* t2b = t2 + (size_t)bth * N_;
    const uint32_t* adjA = adjbits + (size_t)iA * (N_ / 32);
    const uint32_t* adjB = adjbits + (size_t)iB * (N_ / 32);

    // staging: wave w fills quarter w; source j pre-swizzled (slot ^ (d>>1)&3)
    const int sb  = w >> 1;
    const int sd0 = (w & 1) * 64 + (lane >> 2);
    const int sj  = ((lane & 3) ^ ((lane >> 3) & 3)) * 8;
    const unsigned short* gstg = htT + ((size_t)(sb * (T_ * H_) + th) * D_ + sd0) * N_ + sj;
    unsigned short* lstg = stg + (size_t)w * 2048 + (size_t)lane * 8;

#define STAGE(BUF, T) {                                          \
        const unsigned short* gs = gstg + (size_t)(T) * 32;      \
        unsigned short* ls = lstg + (BUF) * 8192;                \
        load_lds16(gs,           ls);                            \
        load_lds16(gs + 16 * N_, ls + 512);                      \
        load_lds16(gs + 32 * N_, ls + 1024);                     \
        load_lds16(gs + 48 * N_, ls + 1536); }

#define LOADSC(S, T) {                                           \
        S.a1l = *(const float4*)(t1b + (T) * 32 + jrel);         \
        S.a1h = *(const float4*)(t1b + (T) * 32 + jrel + 4);     \
        S.a2l = *(const float4*)(t2b + (T) * 32 + jrel);         \
        S.a2h = *(const float4*)(t2b + (T) * 32 + jrel + 4);     \
        S.mA  = adjA[(T)];                                       \
        S.mB  = adjB[(T)]; }

    f32x4 accA[8], accB[8];
    #pragma unroll
    for (int nt = 0; nt < 8; ++nt) {
        accA[nt] = (f32x4){0.f, 0.f, 0.f, 0.f};
        accB[nt] = (f32x4){0.f, 0.f, 0.f, 0.f};
    }
    f32x4 daccA = (f32x4){0.f, 0.f, 0.f, 0.f};
    f32x4 daccB = (f32x4){0.f, 0.f, 0.f, 0.f};
    short8 ones8;
    {
        const short ov = (row16 == 0) ? (short)0x3F80 : (short)0;
        #pragma unroll
        for (int e = 0; e < 8; ++e) ones8[e] = ov;
    }
    const unsigned short* rdbase = stg + b * 4096 + row16 * 32 + kswz;

    SC scX, scY;

#define BODY(T, US, PS, TPF)                                                   \
    asm volatile("s_waitcnt vmcnt(14)" ::: "memory");                          \
    __builtin_amdgcn_s_barrier();                                              \
    asm volatile("" ::: "memory");                                             \
    STAGE(((T) + 3) & 3, ((T) + 3) & 31)                                       \
    LOADSC(PS, (TPF))                                                          \
    {                                                                          \
        const float tj1[8] = {US.a1l.x, US.a1l.y, US.a1l.z, US.a1l.w,          \
                              US.a1h.x, US.a1h.y, US.a1h.z, US.a1h.w};         \
        const float tj2[8] = {US.a2l.x, US.a2l.y, US.a2l.z, US.a2l.w,          \
                              US.a2h.x, US.a2h.y, US.a2h.z, US.a2h.w};         \
        const uint32_t mA = US.mA >> jrel;                                     \
        const uint32_t mB = US.mB >> jrel;                                     \
        float wvA[8], wvB[8];                                                  \
        _Pragma("unroll")                                                      \
        for (int e = 0; e < 8; ++e) {                                          \
            const float eA = fmaxf(s1A + tj1[e], s2A + tj2[e]);                \
            const float eB = fmaxf(s1B + tj1[e], s2B + tj2[e]);                \
            wvA[e] = ((mA >> e) & 1u) ? fexp2(eA) : 0.f;                       \
            wvB[e] = ((mB >> e) & 1u) ? fexp2(eB) : 0.f;                       \
        }                                                                      \
        short8 afA, afB;                                                       \
        _Pragma("unroll")                                                      \
        for (int p = 0; p < 4; ++p) {                                          \
            ((uint32_t*)&afA)[p] = cvt_pk_bf16(wvA[2 * p], wvA[2 * p + 1]);    \
            ((uint32_t*)&afB)[p] = cvt_pk_bf16(wvB[2 * p], wvB[2 * p + 1]);    \
        }                                                                      \
        const unsigned short* rb = rdbase + ((T) & 3) * 8192;                  \
        short8 bfr[8];                                                         \
        _Pragma("unroll")                                                      \
        for (int nt = 0; nt < 8; ++nt) bfr[nt] = *(const short8*)(rb + nt * 512); \
        _Pragma("unroll")                                                      \
        for (int nt = 0; nt < 8; ++nt) {                                       \
            accA[nt] = MFMA16(afA, bfr[nt], accA[nt]);                         \
            accB[nt] = MFMA16(afB, bfr[nt], accB[nt]);                         \
        }                                                                      \
        daccA = MFMA16(afA, ones8, daccA);                                     \
        daccB = MFMA16(afB, ones8, daccB);                                     \
    }

    STAGE(0, 0)
    STAGE(1, 1)
    STAGE(2, 2)
    LOADSC(scX, 0)

    for (int tt = 0; tt < 16; ++tt) {
        const int t0 = tt * 2;
        BODY(t0,     scX, scY, t0 + 1)
        BODY(t0 + 1, scY, scX, (t0 + 2) & 31)
    }
#undef BODY
#undef LOADSC
#undef STAGE

    __syncthreads();   // full drain (incl. dummy stages) before LDS reuse

    // inverse denominators: D[row=kgrp*4+r][0] lives at lane kgrp*16, reg r
    float ivA[4], ivB[4];
    #pragma unroll
    for (int r = 0; r < 4; ++r) {
        ivA[r] = __shfl(1.0f / daccA[r], kgrp * 16);
        ivB[r] = __shfl(1.0f / daccB[r], kgrp * 16);
    }

    // cross-b mean via LDS (reuse stage memory: 64 rows x 128 f32 = 32KB)
    float* comb = (float*)smem;
    if (b == 1) {
        #pragma unroll
        for (int nt = 0; nt < 8; ++nt)
            #pragma unroll
            for (int r = 0; r < 4; ++r) {
                const int il = isub * 32 + kgrp * 4 + r;
                const int d  = nt * 16 + row16;
                comb[il * 128 + d]        = accA[nt][r] * ivA[r];
                comb[(il + 16) * 128 + d] = accB[nt][r] * ivB[r];
            }
    }
    __syncthreads();
    if (b == 0) {
        #pragma unroll
        for (int nt = 0; nt < 8; ++nt)
            #pragma unroll
            for (int r = 0; r < 4; ++r) {
                const int il = isub * 32 + kgrp * 4 + r;
                const int d  = nt * 16 + row16;
                out[((size_t)th * N_ + i0 + il) * D_ + d] =
                    0.5f * (accA[nt][r] * ivA[r] + comb[il * 128 + d]);
                out[((size_t)th * N_ + i0 + il + 16) * D_ + d] =
                    0.5f * (accB[nt][r] * ivB[r] + comb[(il + 16) * 128 + d]);
            }
    }
}

extern "C" void kernel_launch(void* const* d_in, const int* in_sizes, int n_in,
                              void* d_out, int out_size, void* d_ws, size_t ws_size,
                              hipStream_t stream) {
    const float* h   = (const float*)d_in[0];
    const int*   adj = (const int*)d_in[1];
    const float* W   = (const float*)d_in[2];
    const float* a   = (const float*)d_in[3];
    float* out = (float*)d_out;

    // ws: htT 16.78MB | s1,s2,t1,t2 4x256KB | adjbits 128KB | Wt_bf 512KB | wa 16KB
    char* p = (char*)d_ws;
    unsigned short* htT = (unsigned short*)p;  p += (size_t)B_ * T_ * H_ * D_ * N_ * 2;
    float* s1 = (float*)p;                     p += (size_t)B_ * T_ * H_ * N_ * 4;
    float* s2 = (float*)p;                     p += (size_t)B_ * T_ * H_ * N_ * 4;
    float* t1 = (float*)p;                     p += (size_t)B_ * T_ * H_ * N_ * 4;
    float* t2 = (float*)p;                     p += (size_t)B_ * T_ * H_ * N_ * 4;
    uint32_t* adjbits = (uint32_t*)p;          p += (size_t)N_ * N_ / 32 * 4;
    unsigned short* Wt_bf = (unsigned short*)p;p += (size_t)(H_ * D_) * FIN_ * 2;
    float* wa = (float*)p;

    k_prep<<<dim3(208), dim3(256), 0, stream>>>(adj, W, a, Wt_bf, adjbits, wa);
    k_gemm_sp<<<dim3(1152), dim3(256), 0, stream>>>(h, Wt_bf, wa, htT, s1, s2, t1, t2);
    k_attn<<<dim3(512), dim3(256), 0, stream>>>(htT, s1, s2, t1, t2, adjbits, out);
}